// Round 14
// baseline (253.222 us; speedup 1.0000x reference)
//
#include <hip/hip_runtime.h>
#include <hip/hip_bf16.h>
#include <cstdint>

// Toy MultiHeadAttention: B=2, L=2048, D=1024, H=16, HD=64, causal, eval (no dropout)
// Pipeline: fp32->bf16 converts; QKV GEMM (bf16 MFMA) with Q/K/Vt scatter epilogue;
// causal flash attention: r2/r13-PASSING per-tile math, kv range split across
// EIGHT waves (512-thr blocks) + LDS merge; out GEMM + bias (fp32 out).

typedef __attribute__((ext_vector_type(8))) short sh8;    // 8 bf16 in 4 VGPRs (MFMA A/B frag)
typedef __attribute__((ext_vector_type(4))) float f32x4;  // MFMA C/D frag

__device__ __forceinline__ unsigned short f2b(float f) {  // fp32 -> bf16 RNE
  unsigned int u = __float_as_uint(f);
  u += 0x7FFFu + ((u >> 16) & 1u);
  return (unsigned short)(u >> 16);
}

__device__ __forceinline__ unsigned int pack2(float lo, float hi) {  // 2xbf16 in u32
  return (unsigned int)f2b(lo) | ((unsigned int)f2b(hi) << 16);
}

__device__ __forceinline__ void gload_lds16(const void* g, void* l) {
  __builtin_amdgcn_global_load_lds((__attribute__((address_space(1))) void*)g,
                                   (__attribute__((address_space(3))) void*)l,
                                   16, 0, 0);
}

// ---------------- fp32 -> bf16 convert (vectorized) ----------------
__global__ __launch_bounds__(256) void k_cvt(const float* __restrict__ in,
                                             unsigned short* __restrict__ out, int n) {
  int idx = (blockIdx.x * 256 + threadIdx.x) * 4;
  if (idx >= n) return;
  float4 v = *(const float4*)&in[idx];
  union { unsigned short u[4]; uint2 w; } r;
  r.u[0] = f2b(v.x); r.u[1] = f2b(v.y); r.u[2] = f2b(v.z); r.u[3] = f2b(v.w);
  *(uint2*)&out[idx] = r.w;
}

// ---------------- shared GEMM core: C[128x128] = A[M,K] * B[N,K]^T ----------------
__device__ __forceinline__ void gemm_bt_core(
    const unsigned short* __restrict__ A,   // [M][K] bf16 row-major
    const unsigned short* __restrict__ B,   // [N][K] bf16 row-major
    int K, int m0, int n0,
    unsigned short* ldsA, unsigned short* ldsB,
    f32x4 acc[4][4]) {
  const int tid  = threadIdx.x;
  const int wv   = tid >> 6;
  const int lane = tid & 63;
  const int wm = (wv >> 1) << 6;
  const int wn = (wv & 1) << 6;
  const int sr = (wv << 5) + (lane >> 3);
  const int sc = (lane & 7) << 3;
  const int fr = lane & 15;
  const int fk = (lane >> 4) << 3;

  for (int k0 = 0; k0 < K; k0 += 64) {
#pragma unroll
    for (int t = 0; t < 4; ++t) {
      int r = sr + (t << 3);
      gload_lds16(&A[(size_t)(m0 + r) * K + k0 + sc], &ldsA[r * 64 + sc]);
      gload_lds16(&B[(size_t)(n0 + r) * K + k0 + sc], &ldsB[r * 64 + sc]);
    }
    __syncthreads();
#pragma unroll
    for (int ks = 0; ks < 2; ++ks) {
      sh8 af[4], bf[4];
#pragma unroll
      for (int mt = 0; mt < 4; ++mt)
        af[mt] = *(const sh8*)&ldsA[(wm + mt * 16 + fr) * 64 + ks * 32 + fk];
#pragma unroll
      for (int nt = 0; nt < 4; ++nt)
        bf[nt] = *(const sh8*)&ldsB[(wn + nt * 16 + fr) * 64 + ks * 32 + fk];
#pragma unroll
      for (int mt = 0; mt < 4; ++mt)
#pragma unroll
        for (int nt = 0; nt < 4; ++nt)
          acc[mt][nt] = __builtin_amdgcn_mfma_f32_16x16x32_bf16(af[mt], bf[nt], acc[mt][nt], 0, 0, 0);
    }
    __syncthreads();
  }
}

// ---------------- QKV projection + scatter ----------------
__global__ __launch_bounds__(256) void k_qkv_gemm(
    const unsigned short* __restrict__ xb, const unsigned short* __restrict__ wq,
    unsigned short* __restrict__ Q, unsigned short* __restrict__ Kc,
    unsigned short* __restrict__ Vt) {
  __shared__ __align__(16) unsigned short lds[2 * 128 * 64];
  f32x4 acc[4][4];
  const f32x4 fz = {0.f, 0.f, 0.f, 0.f};
#pragma unroll
  for (int i = 0; i < 4; ++i)
#pragma unroll
    for (int j = 0; j < 4; ++j) acc[i][j] = fz;

  const int m0 = blockIdx.x * 128, n0 = blockIdx.y * 128;
  gemm_bt_core(xb, wq, 1024, m0, n0, lds, lds + 128 * 64, acc);

  const int tid = threadIdx.x, wv = tid >> 6, lane = tid & 63;
  const int wm = (wv >> 1) << 6, wn = (wv & 1) << 6;
  const int r4 = (lane >> 4) << 2, fr = lane & 15;
#pragma unroll
  for (int mt = 0; mt < 4; ++mt)
#pragma unroll
    for (int nt = 0; nt < 4; ++nt)
#pragma unroll
      for (int i = 0; i < 4; ++i) {
        int row = m0 + wm + mt * 16 + r4 + i;   // m in [0,4096)
        int col = n0 + wn + nt * 16 + fr;       // n in [0,3072)
        float v = acc[mt][nt][i];
        int b = row >> 11, lq = row & 2047;
        int which = col >> 10, rem = col & 1023;
        int h = rem >> 6, hd = rem & 63;
        size_t bh = (size_t)(b * 16 + h);
        if (which == 0)      Q [(bh * 2048 + lq) * 64 + hd] = f2b(v * 0.125f);
        else if (which == 1) Kc[(bh * 2048 + lq) * 64 + hd] = f2b(v);
        else                 Vt[(bh * 64 + hd) * 2048 + lq] = f2b(v);
      }
}

// ---------------- causal flash attention (8-way kv-split, r2 math per chunk) --------
// grid: 4096 blocks x 512 thr; blockIdx = sIdx*32 + bh; strip = 127 - sIdx (longest
// first, bh fastest). ALL 8 waves work on the SAME 16-row strip; wave wv processes
// kv-tiles [nj*wv/8, nj*(wv+1)/8) with the UNMODIFIED r2/r13 loop. Partials (o,m,l)
// merged in LDS: mm = max_c m_c; o* = sum o_c*e^(m_c-mm); l* likewise.
__global__ __launch_bounds__(512, 8) void k_attn(
    const unsigned short* __restrict__ Q, const unsigned short* __restrict__ Kc,
    const unsigned short* __restrict__ Vt, unsigned short* __restrict__ attn) {
  __shared__ float lds_o[8][64][17];   // [wave][d][q], stride 17 (pad)
  __shared__ float lds_m[8][16], lds_l[8][16];

  const int bh   = blockIdx.x & 31;
  const int strip = 127 - (blockIdx.x >> 5);   // 0..127, longest first
  const int wv = threadIdx.x >> 6, lane = threadIdx.x & 63;
  const int qw = strip << 4;
  const int b = bh >> 4, h = bh & 15;
  const unsigned short* Qb = Q  + (size_t)bh * 2048 * 64;
  const unsigned short* Kb = Kc + (size_t)bh * 2048 * 64;
  const unsigned short* Vb = Vt + (size_t)bh * 64 * 2048;
  const int fr = lane & 15, g = lane >> 4;
  const int fk = g << 3, r4 = g << 2;
  const f32x4 fz = {0.f, 0.f, 0.f, 0.f};
  const bool godd = (g & 1) != 0;
  const bool gup  = g >= 2;
  const bool gswap = godd != gup;         // g==1 || g==2

  sh8 qf[2];
#pragma unroll
  for (int ks = 0; ks < 2; ++ks)
    qf[ks] = *(const sh8*)&Qb[(size_t)(qw + fr) * 64 + ks * 32 + fk];

  f32x4 o[4];
#pragma unroll
  for (int i = 0; i < 4; ++i) o[i] = fz;
  float m_i = -1e30f, l_i = 0.f;

  const int nj = (qw + 47) >> 5;          // 32-kv tiles up to the diagonal
  const int j0 = (nj * wv) >> 3;          // this wave's chunk (8-way)
  const int j1 = (nj * (wv + 1)) >> 3;
  for (int j = j0; j < j1; ++j) {
    const int kvb = j << 5;
    // QK^T swapped: s[t] row = kv (r4+i), col = q (fr)
    f32x4 s[2]; s[0] = fz; s[1] = fz;
#pragma unroll
    for (int t = 0; t < 2; ++t)
#pragma unroll
      for (int ks = 0; ks < 2; ++ks) {
        sh8 kf = *(const sh8*)&Kb[(size_t)(kvb + t * 16 + fr) * 64 + ks * 32 + fk];
        s[t] = __builtin_amdgcn_mfma_f32_16x16x32_bf16(kf, qf[ks], s[t], 0, 0, 0);
      }
    // hoist V loads (independent of softmax) for latency overlap
    sh8 vf[4];
#pragma unroll
    for (int hb = 0; hb < 4; ++hb)
      vf[hb] = *(const sh8*)&Vb[(size_t)(hb * 16 + fr) * 2048 + kvb + fk];

    if (j == nj - 1) {  // diagonal tile: causal mask (kv > q)
#pragma unroll
      for (int t = 0; t < 2; ++t)
#pragma unroll
        for (int i = 0; i < 4; ++i)
          if (kvb + t * 16 + r4 + i > qw + fr) s[t][i] = -1e30f;
    }
    // per-lane softmax for q = qw+fr: within-lane 8-value reduce + xor16 + xor32
    float mx = fmaxf(fmaxf(fmaxf(s[0][0], s[0][1]), fmaxf(s[0][2], s[0][3])),
                     fmaxf(fmaxf(s[1][0], s[1][1]), fmaxf(s[1][2], s[1][3])));
    mx = fmaxf(mx, __shfl_xor(mx, 16, 64));
    mx = fmaxf(mx, __shfl_xor(mx, 32, 64));
    const float mn = fmaxf(m_i, mx);
    const float scale = __expf(m_i - mn);
    m_i = mn;
    float p0[4], p1[4];
#pragma unroll
    for (int i = 0; i < 4; ++i) {
      p0[i] = __expf(s[0][i] - mn);
      p1[i] = __expf(s[1][i] - mn);
    }
    float rs = (p0[0] + p0[1]) + (p0[2] + p0[3]) + (p1[0] + p1[1]) + (p1[2] + p1[3]);
    rs += __shfl_xor(rs, 16, 64);
    rs += __shfl_xor(rs, 32, 64);
    l_i = l_i * scale + rs;
#pragma unroll
    for (int hb = 0; hb < 4; ++hb)
#pragma unroll
      for (int i = 0; i < 4; ++i) o[hb][i] *= scale;

    // ---- build P^T B-frag in registers: lane needs kv = kvb + 8g..8g+7 at col q=fr ----
    unsigned int P0L = pack2(p0[0], p0[1]);   // kv {4g,   4g+1} (t0)
    unsigned int P0H = pack2(p0[2], p0[3]);   // kv {4g+2, 4g+3} (t0)
    unsigned int P1L = pack2(p1[0], p1[1]);   // kv {16+4g, 16+4g+1} (t1)
    unsigned int P1H = pack2(p1[2], p1[3]);   // kv {16+4g+2, 16+4g+3} (t1)
    // xor16: merge pair (g & ~1, g | 1) into 8-kv blocks
    unsigned int x0 = __shfl_xor((int)P0L, 16, 64);
    unsigned int x1 = __shfl_xor((int)P0H, 16, 64);
    unsigned int y0 = __shfl_xor((int)P1L, 16, 64);
    unsigned int y1 = __shfl_xor((int)P1H, 16, 64);
    unsigned int A0 = godd ? x0 : P0L, A1 = godd ? x1 : P0H;
    unsigned int A2 = godd ? P0L : x0, A3 = godd ? P0H : x1;   // t0 block of own pair
    unsigned int B0 = godd ? y0 : P1L, B1 = godd ? y1 : P1H;
    unsigned int B2 = godd ? P1L : y0, B3 = godd ? P1H : y1;   // t1 block of own pair
    // xor32: fetch the other pair's blocks
    unsigned int As0 = __shfl_xor((int)A0, 32, 64), As1 = __shfl_xor((int)A1, 32, 64);
    unsigned int As2 = __shfl_xor((int)A2, 32, 64), As3 = __shfl_xor((int)A3, 32, 64);
    unsigned int Bs0 = __shfl_xor((int)B0, 32, 64), Bs1 = __shfl_xor((int)B1, 32, 64);
    unsigned int Bs2 = __shfl_xor((int)B2, 32, 64), Bs3 = __shfl_xor((int)B3, 32, 64);
    // g0 -> A, g1 -> As, g2 -> Bs, g3 -> B
    union { unsigned int w[4]; sh8 v; } fu;
    fu.w[0] = gswap ? (gup ? Bs0 : As0) : (gup ? B0 : A0);
    fu.w[1] = gswap ? (gup ? Bs1 : As1) : (gup ? B1 : A1);
    fu.w[2] = gswap ? (gup ? Bs2 : As2) : (gup ? B2 : A2);
    fu.w[3] = gswap ? (gup ? Bs3 : As3) : (gup ? B3 : A3);

#pragma unroll
    for (int hb = 0; hb < 4; ++hb)
      o[hb] = __builtin_amdgcn_mfma_f32_16x16x32_bf16(vf[hb], fu.v, o[hb], 0, 0, 0);
  }

  // ---- merge the 8 waves' partials (flash-decode combine) ----
#pragma unroll
  for (int hb = 0; hb < 4; ++hb)
#pragma unroll
    for (int i = 0; i < 4; ++i)
      lds_o[wv][hb * 16 + r4 + i][fr] = o[hb][i];
  if (g == 0) { lds_m[wv][fr] = m_i; lds_l[wv][fr] = l_i; }
  __syncthreads();

  // merge map: thread tid -> q = tid&15, d-pair d0 = (tid>>4)*2 (covers d=0..63)
  const int tid = threadIdx.x;
  const int q = tid & 15;
  const int d0 = (tid >> 4) << 1;
  float mm = lds_m[0][q];
#pragma unroll
  for (int c = 1; c < 8; ++c) mm = fmaxf(mm, lds_m[c][q]);
  float sc[8];
#pragma unroll
  for (int c = 0; c < 8; ++c) sc[c] = __expf(lds_m[c][q] - mm);
  float lt = 0.f;
#pragma unroll
  for (int c = 0; c < 8; ++c) lt += lds_l[c][q] * sc[c];
  const float inv = 1.0f / lt;
  float od0 = 0.f, od1 = 0.f;
#pragma unroll
  for (int c = 0; c < 8; ++c) {
    od0 += lds_o[c][d0][q] * sc[c];
    od1 += lds_o[c][d0 + 1][q] * sc[c];
  }
  // store: row q_global = qw+q, cols h*64 + d0 + {0,1}
  const size_t base = ((size_t)(b * 2048 + qw + q)) * 1024 + h * 64 + d0;
  *(unsigned int*)&attn[base] = pack2(od0 * inv, od1 * inv);
}

// ---------------- output projection + bias (fp32 out) ----------------
__global__ __launch_bounds__(256) void k_out_gemm(
    const unsigned short* __restrict__ attn, const unsigned short* __restrict__ wo,
    const float* __restrict__ bias, float* __restrict__ out) {
  __shared__ __align__(16) unsigned short lds[2 * 128 * 64];
  f32x4 acc[4][4];
  const f32x4 fz = {0.f, 0.f, 0.f, 0.f};
#pragma unroll
  for (int i = 0; i < 4; ++i)
#pragma unroll
    for (int j = 0; j < 4; ++j) acc[i][j] = fz;

  const int m0 = blockIdx.x * 128, n0 = blockIdx.y * 128;
  gemm_bt_core(attn, wo, 1024, m0, n0, lds, lds + 128 * 64, acc);

  const int tid = threadIdx.x, wv = tid >> 6, lane = tid & 63;
  const int wm = (wv >> 1) << 6, wn = (wv & 1) << 6;
  const int r4 = (lane >> 4) << 2, fr = lane & 15;
#pragma unroll
  for (int mt = 0; mt < 4; ++mt)
#pragma unroll
    for (int nt = 0; nt < 4; ++nt)
#pragma unroll
      for (int i = 0; i < 4; ++i) {
        int row = m0 + wm + mt * 16 + r4 + i;
        int col = n0 + wn + nt * 16 + fr;
        out[(size_t)row * 1024 + col] = acc[mt][nt][i] + bias[col];
      }
}

// ---------------- launch ----------------
extern "C" void kernel_launch(void* const* d_in, const int* in_sizes, int n_in,
                              void* d_out, int out_size, void* d_ws, size_t ws_size,
                              hipStream_t stream) {
  const float* x     = (const float*)d_in[0];
  const float* qkv_w = (const float*)d_in[1];
  const float* out_w = (const float*)d_in[2];
  const float* out_b = (const float*)d_in[3];
  float* out = (float*)d_out;

  unsigned short* ws   = (unsigned short*)d_ws;
  unsigned short* xb   = ws;                        // 4096*1024
  unsigned short* wq   = xb  + 4096 * 1024;         // 3072*1024
  unsigned short* wo   = wq  + 3072 * 1024;         // 1024*1024
  unsigned short* Qs   = wo  + 1024 * 1024;         // 32*2048*64
  unsigned short* Ks   = Qs  + 32 * 2048 * 64;      // 32*2048*64
  unsigned short* Vts  = Ks  + 32 * 2048 * 64;      // 32*64*2048
  unsigned short* attn = Vts + 32 * 64 * 2048;      // 4096*1024

  k_cvt<<<4096, 256, 0, stream>>>(x,     xb, 4096 * 1024);
  k_cvt<<<3072, 256, 0, stream>>>(qkv_w, wq, 3072 * 1024);
  k_cvt<<<1024, 256, 0, stream>>>(out_w, wo, 1024 * 1024);
  k_qkv_gemm<<<dim3(32, 24), 256, 0, stream>>>(xb, wq, Qs, Ks, Vts);
  k_attn<<<4096, 512, 0, stream>>>(Qs, Ks, Vts, attn);
  k_out_gemm<<<dim3(32, 8), 256, 0, stream>>>(attn, wo, out_b, out);
}

// Round 15
// 162.109 us; speedup vs baseline: 1.5620x; 1.5620x over previous
//
#include <hip/hip_runtime.h>
#include <hip/hip_bf16.h>
#include <cstdint>

// Toy MultiHeadAttention: B=2, L=2048, D=1024, H=16, HD=64, causal, eval (no dropout)
// Pipeline: fp32->bf16 converts; QKV GEMM (bf16 MFMA) with Q/K/Vt scatter epilogue;
// causal flash attention: 4 waves x 4 adjacent strips per block, K/V staged ONCE
// per kv-tile into double-buffered LDS (global_load_lds, XOR-swizzled source),
// r2-PASSING per-tile math & epilogue unchanged; out GEMM + bias (fp32 out).

typedef __attribute__((ext_vector_type(8))) short sh8;    // 8 bf16 in 4 VGPRs (MFMA A/B frag)
typedef __attribute__((ext_vector_type(4))) float f32x4;  // MFMA C/D frag

__device__ __forceinline__ unsigned short f2b(float f) {  // fp32 -> bf16 RNE
  unsigned int u = __float_as_uint(f);
  u += 0x7FFFu + ((u >> 16) & 1u);
  return (unsigned short)(u >> 16);
}

__device__ __forceinline__ unsigned int pack2(float lo, float hi) {  // 2xbf16 in u32
  return (unsigned int)f2b(lo) | ((unsigned int)f2b(hi) << 16);
}

__device__ __forceinline__ void gload_lds16(const void* g, void* l) {
  __builtin_amdgcn_global_load_lds((__attribute__((address_space(1))) void*)g,
                                   (__attribute__((address_space(3))) void*)l,
                                   16, 0, 0);
}

// ---------------- fp32 -> bf16 convert (vectorized) ----------------
__global__ __launch_bounds__(256) void k_cvt(const float* __restrict__ in,
                                             unsigned short* __restrict__ out, int n) {
  int idx = (blockIdx.x * 256 + threadIdx.x) * 4;
  if (idx >= n) return;
  float4 v = *(const float4*)&in[idx];
  union { unsigned short u[4]; uint2 w; } r;
  r.u[0] = f2b(v.x); r.u[1] = f2b(v.y); r.u[2] = f2b(v.z); r.u[3] = f2b(v.w);
  *(uint2*)&out[idx] = r.w;
}

// ---------------- shared GEMM core: C[128x128] = A[M,K] * B[N,K]^T ----------------
__device__ __forceinline__ void gemm_bt_core(
    const unsigned short* __restrict__ A,   // [M][K] bf16 row-major
    const unsigned short* __restrict__ B,   // [N][K] bf16 row-major
    int K, int m0, int n0,
    unsigned short* ldsA, unsigned short* ldsB,
    f32x4 acc[4][4]) {
  const int tid  = threadIdx.x;
  const int wv   = tid >> 6;
  const int lane = tid & 63;
  const int wm = (wv >> 1) << 6;
  const int wn = (wv & 1) << 6;
  const int sr = (wv << 5) + (lane >> 3);
  const int sc = (lane & 7) << 3;
  const int fr = lane & 15;
  const int fk = (lane >> 4) << 3;

  for (int k0 = 0; k0 < K; k0 += 64) {
#pragma unroll
    for (int t = 0; t < 4; ++t) {
      int r = sr + (t << 3);
      gload_lds16(&A[(size_t)(m0 + r) * K + k0 + sc], &ldsA[r * 64 + sc]);
      gload_lds16(&B[(size_t)(n0 + r) * K + k0 + sc], &ldsB[r * 64 + sc]);
    }
    __syncthreads();
#pragma unroll
    for (int ks = 0; ks < 2; ++ks) {
      sh8 af[4], bf[4];
#pragma unroll
      for (int mt = 0; mt < 4; ++mt)
        af[mt] = *(const sh8*)&ldsA[(wm + mt * 16 + fr) * 64 + ks * 32 + fk];
#pragma unroll
      for (int nt = 0; nt < 4; ++nt)
        bf[nt] = *(const sh8*)&ldsB[(wn + nt * 16 + fr) * 64 + ks * 32 + fk];
#pragma unroll
      for (int mt = 0; mt < 4; ++mt)
#pragma unroll
        for (int nt = 0; nt < 4; ++nt)
          acc[mt][nt] = __builtin_amdgcn_mfma_f32_16x16x32_bf16(af[mt], bf[nt], acc[mt][nt], 0, 0, 0);
    }
    __syncthreads();
  }
}

// ---------------- QKV projection + scatter ----------------
__global__ __launch_bounds__(256) void k_qkv_gemm(
    const unsigned short* __restrict__ xb, const unsigned short* __restrict__ wq,
    unsigned short* __restrict__ Q, unsigned short* __restrict__ Kc,
    unsigned short* __restrict__ Vt) {
  __shared__ __align__(16) unsigned short lds[2 * 128 * 64];
  f32x4 acc[4][4];
  const f32x4 fz = {0.f, 0.f, 0.f, 0.f};
#pragma unroll
  for (int i = 0; i < 4; ++i)
#pragma unroll
    for (int j = 0; j < 4; ++j) acc[i][j] = fz;

  const int m0 = blockIdx.x * 128, n0 = blockIdx.y * 128;
  gemm_bt_core(xb, wq, 1024, m0, n0, lds, lds + 128 * 64, acc);

  const int tid = threadIdx.x, wv = tid >> 6, lane = tid & 63;
  const int wm = (wv >> 1) << 6, wn = (wv & 1) << 6;
  const int r4 = (lane >> 4) << 2, fr = lane & 15;
#pragma unroll
  for (int mt = 0; mt < 4; ++mt)
#pragma unroll
    for (int nt = 0; nt < 4; ++nt)
#pragma unroll
      for (int i = 0; i < 4; ++i) {
        int row = m0 + wm + mt * 16 + r4 + i;   // m in [0,4096)
        int col = n0 + wn + nt * 16 + fr;       // n in [0,3072)
        float v = acc[mt][nt][i];
        int b = row >> 11, lq = row & 2047;
        int which = col >> 10, rem = col & 1023;
        int h = rem >> 6, hd = rem & 63;
        size_t bh = (size_t)(b * 16 + h);
        if (which == 0)      Q [(bh * 2048 + lq) * 64 + hd] = f2b(v * 0.125f);
        else if (which == 1) Kc[(bh * 2048 + lq) * 64 + hd] = f2b(v);
        else                 Vt[(bh * 64 + hd) * 2048 + lq] = f2b(v);
      }
}

// ---------------- causal flash attention (LDS-shared K/V, r2 math) ----------------
// grid: 1024 blocks x 256 thr; blockIdx = gIdx*32 + bh; grp = 31 - gIdx (longest
// first, bh fastest). Wave wv owns strip = grp*4 + wv (16 q-rows, full kv range --
// no kv-split, no merge). All 4 waves lockstep over kv-tiles 0..njm-1 of the
// block's LONGEST strip; K(32x64) + V^T(64x32) staged once per tile into dbuf LDS
// via global_load_lds with XOR-pre-swizzled GLOBAL source (linear LDS dest):
//   K granule: phys = log ^ (row&7)   V granule: phys = log ^ ((row&3)^((row>>2)&3))
// Reads apply the same XOR -> bank-conflict-free (2-way max). One barrier/tile;
// waves with shorter strips skip compute but hit every barrier (njm is uniform).
__global__ __launch_bounds__(256, 4) void k_attn(
    const unsigned short* __restrict__ Q, const unsigned short* __restrict__ Kc,
    const unsigned short* __restrict__ Vt, unsigned short* __restrict__ attn) {
  __shared__ __align__(16) unsigned short kbuf[2][32 * 64];   // 4KB per buf
  __shared__ __align__(16) unsigned short vbuf[2][64 * 32];   // 4KB per buf

  const int bh  = blockIdx.x & 31;
  const int grp = 31 - (blockIdx.x >> 5);      // 0..31, longest first
  const int wv = threadIdx.x >> 6, lane = threadIdx.x & 63;
  const int tid = threadIdx.x;
  const int strip = (grp << 2) + wv;           // 0..127
  const int qw = strip << 4;
  const int b = bh >> 4, h = bh & 15;
  const unsigned short* Qb = Q  + (size_t)bh * 2048 * 64;
  const unsigned short* Kb = Kc + (size_t)bh * 2048 * 64;
  const unsigned short* Vb = Vt + (size_t)bh * 64 * 2048;
  const int fr = lane & 15, g = lane >> 4;
  const int fk = g << 3, r4 = g << 2;
  const f32x4 fz = {0.f, 0.f, 0.f, 0.f};
  const bool godd = (g & 1) != 0;
  const bool gup  = g >= 2;
  const bool gswap = godd != gup;              // g==1 || g==2
  const int vswz = (fr & 3) ^ ((fr >> 2) & 3); // V read-granule swizzle

  // staging: thread t covers one 16B granule of K and one of V per tile
  const int ksrow = tid >> 3, kslog = (tid & 7) ^ (ksrow & 7);
  const int vsrow = tid >> 2, vslog = (tid & 3) ^ ((vsrow & 3) ^ ((vsrow >> 2) & 3));

  sh8 qf[2];
#pragma unroll
  for (int ks = 0; ks < 2; ++ks)
    qf[ks] = *(const sh8*)&Qb[(size_t)(qw + fr) * 64 + ks * 32 + fk];

  f32x4 o[4];
#pragma unroll
  for (int i = 0; i < 4; ++i) o[i] = fz;
  float m_i = -1e30f, l_i = 0.f;

  const int njw = (qw + 47) >> 5;              // this wave's tiles (incl. diagonal)
  const int njm = ((grp << 6) + 95) >> 5;      // block max (longest strip)

  // stage tile 0 into buf 0
  gload_lds16(&Kb[(size_t)ksrow * 64 + kslog * 8], &kbuf[0][tid * 8]);
  gload_lds16(&Vb[(size_t)vsrow * 2048 + vslog * 8], &vbuf[0][tid * 8]);

  for (int j = 0; j < njm; ++j) {
    __syncthreads();   // stage(j) complete (vmcnt drain); compute(j-1) done
    if (j + 1 < njm) {
      const int kvn = (j + 1) << 5;
      const int nb = (j + 1) & 1;
      gload_lds16(&Kb[(size_t)(kvn + ksrow) * 64 + kslog * 8], &kbuf[nb][tid * 8]);
      gload_lds16(&Vb[(size_t)vsrow * 2048 + kvn + vslog * 8], &vbuf[nb][tid * 8]);
    }
    if (j < njw) {
      const int kvb = j << 5;
      const unsigned short* kb = kbuf[j & 1];
      const unsigned short* vb = vbuf[j & 1];
      // QK^T swapped: s[t] row = kv (r4+i), col = q (fr)
      f32x4 s[2]; s[0] = fz; s[1] = fz;
#pragma unroll
      for (int t = 0; t < 2; ++t)
#pragma unroll
        for (int ks = 0; ks < 2; ++ks) {
          sh8 kf = *(const sh8*)&kb[(t * 16 + fr) * 64 + ((((ks << 2) + g) ^ (fr & 7)) << 3)];
          s[t] = __builtin_amdgcn_mfma_f32_16x16x32_bf16(kf, qf[ks], s[t], 0, 0, 0);
        }
      sh8 vf[4];
#pragma unroll
      for (int hb = 0; hb < 4; ++hb)
        vf[hb] = *(const sh8*)&vb[(hb * 16 + fr) * 32 + ((g ^ vswz) << 3)];

      if (j == njw - 1) {  // diagonal tile: causal mask (kv > q)
#pragma unroll
        for (int t = 0; t < 2; ++t)
#pragma unroll
          for (int i = 0; i < 4; ++i)
            if (kvb + t * 16 + r4 + i > qw + fr) s[t][i] = -1e30f;
      }
      // per-lane softmax for q = qw+fr: within-lane 8-value reduce + xor16 + xor32
      float mx = fmaxf(fmaxf(fmaxf(s[0][0], s[0][1]), fmaxf(s[0][2], s[0][3])),
                       fmaxf(fmaxf(s[1][0], s[1][1]), fmaxf(s[1][2], s[1][3])));
      mx = fmaxf(mx, __shfl_xor(mx, 16, 64));
      mx = fmaxf(mx, __shfl_xor(mx, 32, 64));
      const float mn = fmaxf(m_i, mx);
      const float scale = __expf(m_i - mn);
      m_i = mn;
      float p0[4], p1[4];
#pragma unroll
      for (int i = 0; i < 4; ++i) {
        p0[i] = __expf(s[0][i] - mn);
        p1[i] = __expf(s[1][i] - mn);
      }
      float rs = (p0[0] + p0[1]) + (p0[2] + p0[3]) + (p1[0] + p1[1]) + (p1[2] + p1[3]);
      rs += __shfl_xor(rs, 16, 64);
      rs += __shfl_xor(rs, 32, 64);
      l_i = l_i * scale + rs;
#pragma unroll
      for (int hb = 0; hb < 4; ++hb)
#pragma unroll
        for (int i = 0; i < 4; ++i) o[hb][i] *= scale;

      // ---- build P^T B-frag in registers (r2): lane needs kv = kvb+8g..8g+7, col q=fr ----
      unsigned int P0L = pack2(p0[0], p0[1]);
      unsigned int P0H = pack2(p0[2], p0[3]);
      unsigned int P1L = pack2(p1[0], p1[1]);
      unsigned int P1H = pack2(p1[2], p1[3]);
      unsigned int x0 = __shfl_xor((int)P0L, 16, 64);
      unsigned int x1 = __shfl_xor((int)P0H, 16, 64);
      unsigned int y0 = __shfl_xor((int)P1L, 16, 64);
      unsigned int y1 = __shfl_xor((int)P1H, 16, 64);
      unsigned int A0 = godd ? x0 : P0L, A1 = godd ? x1 : P0H;
      unsigned int A2 = godd ? P0L : x0, A3 = godd ? P0H : x1;
      unsigned int B0 = godd ? y0 : P1L, B1 = godd ? y1 : P1H;
      unsigned int B2 = godd ? P1L : y0, B3 = godd ? P1H : y1;
      unsigned int As0 = __shfl_xor((int)A0, 32, 64), As1 = __shfl_xor((int)A1, 32, 64);
      unsigned int As2 = __shfl_xor((int)A2, 32, 64), As3 = __shfl_xor((int)A3, 32, 64);
      unsigned int Bs0 = __shfl_xor((int)B0, 32, 64), Bs1 = __shfl_xor((int)B1, 32, 64);
      unsigned int Bs2 = __shfl_xor((int)B2, 32, 64), Bs3 = __shfl_xor((int)B3, 32, 64);
      union { unsigned int w[4]; sh8 v; } fu;
      fu.w[0] = gswap ? (gup ? Bs0 : As0) : (gup ? B0 : A0);
      fu.w[1] = gswap ? (gup ? Bs1 : As1) : (gup ? B1 : A1);
      fu.w[2] = gswap ? (gup ? Bs2 : As2) : (gup ? B2 : A2);
      fu.w[3] = gswap ? (gup ? Bs3 : As3) : (gup ? B3 : A3);

#pragma unroll
      for (int hb = 0; hb < 4; ++hb)
        o[hb] = __builtin_amdgcn_mfma_f32_16x16x32_bf16(vf[hb], fu.v, o[hb], 0, 0, 0);
    }
  }

  const float inv = 1.0f / l_i;
  // o layout: col = q = fr (lane), row = d = hb*16 + r4 + i -> pack i-pairs, b32 stores
  const size_t base = ((size_t)(b * 2048 + qw + fr)) * 1024 + h * 64;
#pragma unroll
  for (int hb = 0; hb < 4; ++hb)
#pragma unroll
    for (int i2 = 0; i2 < 2; ++i2) {
      unsigned int pw = pack2(o[hb][2 * i2] * inv, o[hb][2 * i2 + 1] * inv);
      *(unsigned int*)&attn[base + hb * 16 + r4 + 2 * i2] = pw;
    }
}

// ---------------- output projection + bias (fp32 out) ----------------
__global__ __launch_bounds__(256) void k_out_gemm(
    const unsigned short* __restrict__ attn, const unsigned short* __restrict__ wo,
    const float* __restrict__ bias, float* __restrict__ out) {
  __shared__ __align__(16) unsigned short lds[2 * 128 * 64];
  f32x4 acc[4][4];
  const f32x4 fz = {0.f, 0.f, 0.f, 0.f};
#pragma unroll
  for (int i = 0; i < 4; ++i)
#pragma unroll
    for (int j = 0; j < 4; ++j) acc[i][j] = fz;

  const int m0 = blockIdx.x * 128, n0 = blockIdx.y * 128;
  gemm_bt_core(attn, wo, 1024, m0, n0, lds, lds + 128 * 64, acc);

  const int tid = threadIdx.x, wv = tid >> 6, lane = tid & 63;
  const int wm = (wv >> 1) << 6, wn = (wv & 1) << 6;
  const int r4 = (lane >> 4) << 2, fr = lane & 15;
#pragma unroll
  for (int mt = 0; mt < 4; ++mt)
#pragma unroll
    for (int nt = 0; nt < 4; ++nt)
#pragma unroll
      for (int i = 0; i < 4; ++i) {
        int row = m0 + wm + mt * 16 + r4 + i;
        int col = n0 + wn + nt * 16 + fr;
        out[(size_t)row * 1024 + col] = acc[mt][nt][i] + bias[col];
      }
}

// ---------------- launch ----------------
extern "C" void kernel_launch(void* const* d_in, const int* in_sizes, int n_in,
                              void* d_out, int out_size, void* d_ws, size_t ws_size,
                              hipStream_t stream) {
  const float* x     = (const float*)d_in[0];
  const float* qkv_w = (const float*)d_in[1];
  const float* out_w = (const float*)d_in[2];
  const float* out_b = (const float*)d_in[3];
  float* out = (float*)d_out;

  unsigned short* ws   = (unsigned short*)d_ws;
  unsigned short* xb   = ws;                        // 4096*1024
  unsigned short* wq   = xb  + 4096 * 1024;         // 3072*1024
  unsigned short* wo   = wq  + 3072 * 1024;         // 1024*1024
  unsigned short* Qs   = wo  + 1024 * 1024;         // 32*2048*64
  unsigned short* Ks   = Qs  + 32 * 2048 * 64;      // 32*2048*64
  unsigned short* Vts  = Ks  + 32 * 2048 * 64;      // 32*64*2048
  unsigned short* attn = Vts + 32 * 64 * 2048;      // 4096*1024

  k_cvt<<<4096, 256, 0, stream>>>(x,     xb, 4096 * 1024);
  k_cvt<<<3072, 256, 0, stream>>>(qkv_w, wq, 3072 * 1024);
  k_cvt<<<1024, 256, 0, stream>>>(out_w, wo, 1024 * 1024);
  k_qkv_gemm<<<dim3(32, 24), 256, 0, stream>>>(xb, wq, Qs, Ks, Vts);
  k_attn<<<1024, 256, 0, stream>>>(Qs, Ks, Vts, attn);
  k_out_gemm<<<dim3(32, 8), 256, 0, stream>>>(attn, wo, out_b, out);
}

// Round 16
// 147.299 us; speedup vs baseline: 1.7191x; 1.1005x over previous
//
#include <hip/hip_runtime.h>
#include <hip/hip_bf16.h>
#include <cstdint>

// Toy MultiHeadAttention: B=2, L=2048, D=1024, H=16, HD=64, causal, eval (no dropout)
// Pipeline: fp32->bf16 converts; QKV GEMM (bf16 MFMA, T2-swizzled LDS) with Q/K/Vt
// scatter epilogue (Vt pack2); causal flash attention (r15-PASSING, LDS-shared K/V);
// out GEMM + bias (fp32 out).

typedef __attribute__((ext_vector_type(8))) short sh8;    // 8 bf16 in 4 VGPRs (MFMA A/B frag)
typedef __attribute__((ext_vector_type(4))) float f32x4;  // MFMA C/D frag

__device__ __forceinline__ unsigned short f2b(float f) {  // fp32 -> bf16 RNE
  unsigned int u = __float_as_uint(f);
  u += 0x7FFFu + ((u >> 16) & 1u);
  return (unsigned short)(u >> 16);
}

__device__ __forceinline__ unsigned int pack2(float lo, float hi) {  // 2xbf16 in u32
  return (unsigned int)f2b(lo) | ((unsigned int)f2b(hi) << 16);
}

__device__ __forceinline__ void gload_lds16(const void* g, void* l) {
  __builtin_amdgcn_global_load_lds((__attribute__((address_space(1))) void*)g,
                                   (__attribute__((address_space(3))) void*)l,
                                   16, 0, 0);
}

// ---------------- fp32 -> bf16 convert (vectorized) ----------------
__global__ __launch_bounds__(256) void k_cvt(const float* __restrict__ in,
                                             unsigned short* __restrict__ out, int n) {
  int idx = (blockIdx.x * 256 + threadIdx.x) * 4;
  if (idx >= n) return;
  float4 v = *(const float4*)&in[idx];
  union { unsigned short u[4]; uint2 w; } r;
  r.u[0] = f2b(v.x); r.u[1] = f2b(v.y); r.u[2] = f2b(v.z); r.u[3] = f2b(v.w);
  *(uint2*)&out[idx] = r.w;
}

// ---------------- shared GEMM core: C[128x128] = A[M,K] * B[N,K]^T ----------------
// T2 XOR-swizzled LDS (r15-attn-validated pattern): linear LDS dest for
// global_load_lds; GLOBAL source granule = (lane&7)^((lane>>3)&7) so LDS slot s of
// row r holds global granule s^(r&7); fragment reads use slot ((ks*4+g)^(fr&7)).
// Spreads each ds_read_b128 over all 8 granule-columns (was 4 -> 16-way conflict).
__device__ __forceinline__ void gemm_bt_core(
    const unsigned short* __restrict__ A,   // [M][K] bf16 row-major
    const unsigned short* __restrict__ B,   // [N][K] bf16 row-major
    int K, int m0, int n0,
    unsigned short* ldsA, unsigned short* ldsB,
    f32x4 acc[4][4]) {
  const int tid  = threadIdx.x;
  const int wv   = tid >> 6;
  const int lane = tid & 63;
  const int wm = (wv >> 1) << 6;
  const int wn = (wv & 1) << 6;
  const int sr = (wv << 5) + (lane >> 3);   // staging row base (t adds 8s: r&7 const)
  const int sc  = (lane & 7) << 3;                          // linear LDS slot (dest)
  const int scg = (((lane & 7) ^ ((lane >> 3) & 7))) << 3;  // swizzled GLOBAL granule
  const int fr = lane & 15;
  const int g  = lane >> 4;

  for (int k0 = 0; k0 < K; k0 += 64) {
#pragma unroll
    for (int t = 0; t < 4; ++t) {
      int r = sr + (t << 3);
      gload_lds16(&A[(size_t)(m0 + r) * K + k0 + scg], &ldsA[r * 64 + sc]);
      gload_lds16(&B[(size_t)(n0 + r) * K + k0 + scg], &ldsB[r * 64 + sc]);
    }
    __syncthreads();
#pragma unroll
    for (int ks = 0; ks < 2; ++ks) {
      sh8 af[4], bf[4];
#pragma unroll
      for (int mt = 0; mt < 4; ++mt)
        af[mt] = *(const sh8*)&ldsA[(wm + mt * 16 + fr) * 64 +
                                    ((((ks << 2) + g) ^ (fr & 7)) << 3)];
#pragma unroll
      for (int nt = 0; nt < 4; ++nt)
        bf[nt] = *(const sh8*)&ldsB[(wn + nt * 16 + fr) * 64 +
                                    ((((ks << 2) + g) ^ (fr & 7)) << 3)];
#pragma unroll
      for (int mt = 0; mt < 4; ++mt)
#pragma unroll
        for (int nt = 0; nt < 4; ++nt)
          acc[mt][nt] = __builtin_amdgcn_mfma_f32_16x16x32_bf16(af[mt], bf[nt], acc[mt][nt], 0, 0, 0);
    }
    __syncthreads();
  }
}

// ---------------- QKV projection + scatter ----------------
__global__ __launch_bounds__(256) void k_qkv_gemm(
    const unsigned short* __restrict__ xb, const unsigned short* __restrict__ wq,
    unsigned short* __restrict__ Q, unsigned short* __restrict__ Kc,
    unsigned short* __restrict__ Vt) {
  __shared__ __align__(16) unsigned short lds[2 * 128 * 64];
  f32x4 acc[4][4];
  const f32x4 fz = {0.f, 0.f, 0.f, 0.f};
#pragma unroll
  for (int i = 0; i < 4; ++i)
#pragma unroll
    for (int j = 0; j < 4; ++j) acc[i][j] = fz;

  const int m0 = blockIdx.x * 128, n0 = blockIdx.y * 128;
  gemm_bt_core(xb, wq, 1024, m0, n0, lds, lds + 128 * 64, acc);

  const int tid = threadIdx.x, wv = tid >> 6, lane = tid & 63;
  const int wm = (wv >> 1) << 6, wn = (wv & 1) << 6;
  const int r4 = (lane >> 4) << 2, fr = lane & 15;
#pragma unroll
  for (int mt = 0; mt < 4; ++mt)
#pragma unroll
    for (int nt = 0; nt < 4; ++nt) {
      const int row0 = m0 + wm + mt * 16 + r4;   // 4-row group, never straddles b
      const int col  = n0 + wn + nt * 16 + fr;   // n in [0,3072)
      const int b = row0 >> 11;
      const int which = col >> 10, rem = col & 1023;
      const int h = rem >> 6, hd = rem & 63;
      const size_t bh = (size_t)(b * 16 + h);
      if (which == 2) {
        // V^T: rows are contiguous in Vt -> pack i-pairs, b32 stores (half the stores)
        const size_t vb = (bh * 64 + hd) * 2048 + (row0 & 2047);
        *(unsigned int*)&Vt[vb]     = pack2(acc[mt][nt][0], acc[mt][nt][1]);
        *(unsigned int*)&Vt[vb + 2] = pack2(acc[mt][nt][2], acc[mt][nt][3]);
      } else {
#pragma unroll
        for (int i = 0; i < 4; ++i) {
          const int lq = (row0 + i) & 2047;
          float v = acc[mt][nt][i];
          if (which == 0) Q [(bh * 2048 + lq) * 64 + hd] = f2b(v * 0.125f);
          else            Kc[(bh * 2048 + lq) * 64 + hd] = f2b(v);
        }
      }
    }
}

// ---------------- causal flash attention (LDS-shared K/V, r2 math) ----------------
// == UNCHANGED from round-15 PASSING kernel ==
__global__ __launch_bounds__(256, 4) void k_attn(
    const unsigned short* __restrict__ Q, const unsigned short* __restrict__ Kc,
    const unsigned short* __restrict__ Vt, unsigned short* __restrict__ attn) {
  __shared__ __align__(16) unsigned short kbuf[2][32 * 64];   // 4KB per buf
  __shared__ __align__(16) unsigned short vbuf[2][64 * 32];   // 4KB per buf

  const int bh  = blockIdx.x & 31;
  const int grp = 31 - (blockIdx.x >> 5);      // 0..31, longest first
  const int wv = threadIdx.x >> 6, lane = threadIdx.x & 63;
  const int tid = threadIdx.x;
  const int strip = (grp << 2) + wv;           // 0..127
  const int qw = strip << 4;
  const int b = bh >> 4, h = bh & 15;
  const unsigned short* Qb = Q  + (size_t)bh * 2048 * 64;
  const unsigned short* Kb = Kc + (size_t)bh * 2048 * 64;
  const unsigned short* Vb = Vt + (size_t)bh * 64 * 2048;
  const int fr = lane & 15, g = lane >> 4;
  const int fk = g << 3, r4 = g << 2;
  const f32x4 fz = {0.f, 0.f, 0.f, 0.f};
  const bool godd = (g & 1) != 0;
  const bool gup  = g >= 2;
  const bool gswap = godd != gup;              // g==1 || g==2
  const int vswz = (fr & 3) ^ ((fr >> 2) & 3); // V read-granule swizzle

  const int ksrow = tid >> 3, kslog = (tid & 7) ^ (ksrow & 7);
  const int vsrow = tid >> 2, vslog = (tid & 3) ^ ((vsrow & 3) ^ ((vsrow >> 2) & 3));

  sh8 qf[2];
#pragma unroll
  for (int ks = 0; ks < 2; ++ks)
    qf[ks] = *(const sh8*)&Qb[(size_t)(qw + fr) * 64 + ks * 32 + fk];

  f32x4 o[4];
#pragma unroll
  for (int i = 0; i < 4; ++i) o[i] = fz;
  float m_i = -1e30f, l_i = 0.f;

  const int njw = (qw + 47) >> 5;              // this wave's tiles (incl. diagonal)
  const int njm = ((grp << 6) + 95) >> 5;      // block max (longest strip)

  gload_lds16(&Kb[(size_t)ksrow * 64 + kslog * 8], &kbuf[0][tid * 8]);
  gload_lds16(&Vb[(size_t)vsrow * 2048 + vslog * 8], &vbuf[0][tid * 8]);

  for (int j = 0; j < njm; ++j) {
    __syncthreads();   // stage(j) complete (vmcnt drain); compute(j-1) done
    if (j + 1 < njm) {
      const int kvn = (j + 1) << 5;
      const int nb = (j + 1) & 1;
      gload_lds16(&Kb[(size_t)(kvn + ksrow) * 64 + kslog * 8], &kbuf[nb][tid * 8]);
      gload_lds16(&Vb[(size_t)vsrow * 2048 + kvn + vslog * 8], &vbuf[nb][tid * 8]);
    }
    if (j < njw) {
      const int kvb = j << 5;
      const unsigned short* kb = kbuf[j & 1];
      const unsigned short* vb = vbuf[j & 1];
      f32x4 s[2]; s[0] = fz; s[1] = fz;
#pragma unroll
      for (int t = 0; t < 2; ++t)
#pragma unroll
        for (int ks = 0; ks < 2; ++ks) {
          sh8 kf = *(const sh8*)&kb[(t * 16 + fr) * 64 + ((((ks << 2) + g) ^ (fr & 7)) << 3)];
          s[t] = __builtin_amdgcn_mfma_f32_16x16x32_bf16(kf, qf[ks], s[t], 0, 0, 0);
        }
      sh8 vf[4];
#pragma unroll
      for (int hb = 0; hb < 4; ++hb)
        vf[hb] = *(const sh8*)&vb[(hb * 16 + fr) * 32 + ((g ^ vswz) << 3)];

      if (j == njw - 1) {  // diagonal tile: causal mask (kv > q)
#pragma unroll
        for (int t = 0; t < 2; ++t)
#pragma unroll
          for (int i = 0; i < 4; ++i)
            if (kvb + t * 16 + r4 + i > qw + fr) s[t][i] = -1e30f;
      }
      float mx = fmaxf(fmaxf(fmaxf(s[0][0], s[0][1]), fmaxf(s[0][2], s[0][3])),
                       fmaxf(fmaxf(s[1][0], s[1][1]), fmaxf(s[1][2], s[1][3])));
      mx = fmaxf(mx, __shfl_xor(mx, 16, 64));
      mx = fmaxf(mx, __shfl_xor(mx, 32, 64));
      const float mn = fmaxf(m_i, mx);
      const float scale = __expf(m_i - mn);
      m_i = mn;
      float p0[4], p1[4];
#pragma unroll
      for (int i = 0; i < 4; ++i) {
        p0[i] = __expf(s[0][i] - mn);
        p1[i] = __expf(s[1][i] - mn);
      }
      float rs = (p0[0] + p0[1]) + (p0[2] + p0[3]) + (p1[0] + p1[1]) + (p1[2] + p1[3]);
      rs += __shfl_xor(rs, 16, 64);
      rs += __shfl_xor(rs, 32, 64);
      l_i = l_i * scale + rs;
#pragma unroll
      for (int hb = 0; hb < 4; ++hb)
#pragma unroll
        for (int i = 0; i < 4; ++i) o[hb][i] *= scale;

      unsigned int P0L = pack2(p0[0], p0[1]);
      unsigned int P0H = pack2(p0[2], p0[3]);
      unsigned int P1L = pack2(p1[0], p1[1]);
      unsigned int P1H = pack2(p1[2], p1[3]);
      unsigned int x0 = __shfl_xor((int)P0L, 16, 64);
      unsigned int x1 = __shfl_xor((int)P0H, 16, 64);
      unsigned int y0 = __shfl_xor((int)P1L, 16, 64);
      unsigned int y1 = __shfl_xor((int)P1H, 16, 64);
      unsigned int A0 = godd ? x0 : P0L, A1 = godd ? x1 : P0H;
      unsigned int A2 = godd ? P0L : x0, A3 = godd ? P0H : x1;
      unsigned int B0 = godd ? y0 : P1L, B1 = godd ? y1 : P1H;
      unsigned int B2 = godd ? P1L : y0, B3 = godd ? P1H : y1;
      unsigned int As0 = __shfl_xor((int)A0, 32, 64), As1 = __shfl_xor((int)A1, 32, 64);
      unsigned int As2 = __shfl_xor((int)A2, 32, 64), As3 = __shfl_xor((int)A3, 32, 64);
      unsigned int Bs0 = __shfl_xor((int)B0, 32, 64), Bs1 = __shfl_xor((int)B1, 32, 64);
      unsigned int Bs2 = __shfl_xor((int)B2, 32, 64), Bs3 = __shfl_xor((int)B3, 32, 64);
      union { unsigned int w[4]; sh8 v; } fu;
      fu.w[0] = gswap ? (gup ? Bs0 : As0) : (gup ? B0 : A0);
      fu.w[1] = gswap ? (gup ? Bs1 : As1) : (gup ? B1 : A1);
      fu.w[2] = gswap ? (gup ? Bs2 : As2) : (gup ? B2 : A2);
      fu.w[3] = gswap ? (gup ? Bs3 : As3) : (gup ? B3 : A3);

#pragma unroll
      for (int hb = 0; hb < 4; ++hb)
        o[hb] = __builtin_amdgcn_mfma_f32_16x16x32_bf16(vf[hb], fu.v, o[hb], 0, 0, 0);
    }
  }

  const float inv = 1.0f / l_i;
  const size_t base = ((size_t)(b * 2048 + qw + fr)) * 1024 + h * 64;
#pragma unroll
  for (int hb = 0; hb < 4; ++hb)
#pragma unroll
    for (int i2 = 0; i2 < 2; ++i2) {
      unsigned int pw = pack2(o[hb][2 * i2] * inv, o[hb][2 * i2 + 1] * inv);
      *(unsigned int*)&attn[base + hb * 16 + r4 + 2 * i2] = pw;
    }
}

// ---------------- output projection + bias (fp32 out) ----------------
__global__ __launch_bounds__(256) void k_out_gemm(
    const unsigned short* __restrict__ attn, const unsigned short* __restrict__ wo,
    const float* __restrict__ bias, float* __restrict__ out) {
  __shared__ __align__(16) unsigned short lds[2 * 128 * 64];
  f32x4 acc[4][4];
  const f32x4 fz = {0.f, 0.f, 0.f, 0.f};
#pragma unroll
  for (int i = 0; i < 4; ++i)
#pragma unroll
    for (int j = 0; j < 4; ++j) acc[i][j] = fz;

  const int m0 = blockIdx.x * 128, n0 = blockIdx.y * 128;
  gemm_bt_core(attn, wo, 1024, m0, n0, lds, lds + 128 * 64, acc);

  const int tid = threadIdx.x, wv = tid >> 6, lane = tid & 63;
  const int wm = (wv >> 1) << 6, wn = (wv & 1) << 6;
  const int r4 = (lane >> 4) << 2, fr = lane & 15;
#pragma unroll
  for (int mt = 0; mt < 4; ++mt)
#pragma unroll
    for (int nt = 0; nt < 4; ++nt)
#pragma unroll
      for (int i = 0; i < 4; ++i) {
        int row = m0 + wm + mt * 16 + r4 + i;
        int col = n0 + wn + nt * 16 + fr;
        out[(size_t)row * 1024 + col] = acc[mt][nt][i] + bias[col];
      }
}

// ---------------- launch ----------------
extern "C" void kernel_launch(void* const* d_in, const int* in_sizes, int n_in,
                              void* d_out, int out_size, void* d_ws, size_t ws_size,
                              hipStream_t stream) {
  const float* x     = (const float*)d_in[0];
  const float* qkv_w = (const float*)d_in[1];
  const float* out_w = (const float*)d_in[2];
  const float* out_b = (const float*)d_in[3];
  float* out = (float*)d_out;

  unsigned short* ws   = (unsigned short*)d_ws;
  unsigned short* xb   = ws;                        // 4096*1024
  unsigned short* wq   = xb  + 4096 * 1024;         // 3072*1024
  unsigned short* wo   = wq  + 3072 * 1024;         // 1024*1024
  unsigned short* Qs   = wo  + 1024 * 1024;         // 32*2048*64
  unsigned short* Ks   = Qs  + 32 * 2048 * 64;      // 32*2048*64
  unsigned short* Vts  = Ks  + 32 * 2048 * 64;      // 32*64*2048
  unsigned short* attn = Vts + 32 * 64 * 2048;      // 4096*1024

  k_cvt<<<4096, 256, 0, stream>>>(x,     xb, 4096 * 1024);
  k_cvt<<<3072, 256, 0, stream>>>(qkv_w, wq, 3072 * 1024);
  k_cvt<<<1024, 256, 0, stream>>>(out_w, wo, 1024 * 1024);
  k_qkv_gemm<<<dim3(32, 24), 256, 0, stream>>>(xb, wq, Qs, Ks, Vts);
  k_attn<<<1024, 256, 0, stream>>>(Qs, Ks, Vts, attn);
  k_out_gemm<<<dim3(32, 8), 256, 0, stream>>>(attn, wo, out_b, out);
}

// Round 17
// 139.724 us; speedup vs baseline: 1.8123x; 1.0542x over previous
//
#include <hip/hip_runtime.h>
#include <hip/hip_bf16.h>
#include <cstdint>

// Toy MultiHeadAttention: B=2, L=2048, D=1024, H=16, HD=64, causal, eval (no dropout)
// Pipeline: fp32->bf16 converts; QKV GEMM (bf16 MFMA, T2-swizzled LDS) with Q/K/Vt
// scatter epilogue (Vt pack2); causal flash attention (r16-PASSING structure +
// r7-validated defer-max T13); out GEMM + bias (fp32 out).

typedef __attribute__((ext_vector_type(8))) short sh8;    // 8 bf16 in 4 VGPRs (MFMA A/B frag)
typedef __attribute__((ext_vector_type(4))) float f32x4;  // MFMA C/D frag

__device__ __forceinline__ unsigned short f2b(float f) {  // fp32 -> bf16 RNE
  unsigned int u = __float_as_uint(f);
  u += 0x7FFFu + ((u >> 16) & 1u);
  return (unsigned short)(u >> 16);
}

__device__ __forceinline__ unsigned int pack2(float lo, float hi) {  // 2xbf16 in u32
  return (unsigned int)f2b(lo) | ((unsigned int)f2b(hi) << 16);
}

__device__ __forceinline__ void gload_lds16(const void* g, void* l) {
  __builtin_amdgcn_global_load_lds((__attribute__((address_space(1))) void*)g,
                                   (__attribute__((address_space(3))) void*)l,
                                   16, 0, 0);
}

// ---------------- fp32 -> bf16 convert (vectorized) ----------------
__global__ __launch_bounds__(256) void k_cvt(const float* __restrict__ in,
                                             unsigned short* __restrict__ out, int n) {
  int idx = (blockIdx.x * 256 + threadIdx.x) * 4;
  if (idx >= n) return;
  float4 v = *(const float4*)&in[idx];
  union { unsigned short u[4]; uint2 w; } r;
  r.u[0] = f2b(v.x); r.u[1] = f2b(v.y); r.u[2] = f2b(v.z); r.u[3] = f2b(v.w);
  *(uint2*)&out[idx] = r.w;
}

// ---------------- shared GEMM core: C[128x128] = A[M,K] * B[N,K]^T ----------------
// T2 XOR-swizzled LDS (r15/r16-validated): linear LDS dest for global_load_lds;
// GLOBAL source granule = (lane&7)^((lane>>3)&7); reads use slot ((ks*4+g)^(fr&7)).
__device__ __forceinline__ void gemm_bt_core(
    const unsigned short* __restrict__ A,   // [M][K] bf16 row-major
    const unsigned short* __restrict__ B,   // [N][K] bf16 row-major
    int K, int m0, int n0,
    unsigned short* ldsA, unsigned short* ldsB,
    f32x4 acc[4][4]) {
  const int tid  = threadIdx.x;
  const int wv   = tid >> 6;
  const int lane = tid & 63;
  const int wm = (wv >> 1) << 6;
  const int wn = (wv & 1) << 6;
  const int sr = (wv << 5) + (lane >> 3);
  const int sc  = (lane & 7) << 3;                          // linear LDS slot (dest)
  const int scg = (((lane & 7) ^ ((lane >> 3) & 7))) << 3;  // swizzled GLOBAL granule
  const int fr = lane & 15;
  const int g  = lane >> 4;

  for (int k0 = 0; k0 < K; k0 += 64) {
#pragma unroll
    for (int t = 0; t < 4; ++t) {
      int r = sr + (t << 3);
      gload_lds16(&A[(size_t)(m0 + r) * K + k0 + scg], &ldsA[r * 64 + sc]);
      gload_lds16(&B[(size_t)(n0 + r) * K + k0 + scg], &ldsB[r * 64 + sc]);
    }
    __syncthreads();
#pragma unroll
    for (int ks = 0; ks < 2; ++ks) {
      sh8 af[4], bf[4];
#pragma unroll
      for (int mt = 0; mt < 4; ++mt)
        af[mt] = *(const sh8*)&ldsA[(wm + mt * 16 + fr) * 64 +
                                    ((((ks << 2) + g) ^ (fr & 7)) << 3)];
#pragma unroll
      for (int nt = 0; nt < 4; ++nt)
        bf[nt] = *(const sh8*)&ldsB[(wn + nt * 16 + fr) * 64 +
                                    ((((ks << 2) + g) ^ (fr & 7)) << 3)];
#pragma unroll
      for (int mt = 0; mt < 4; ++mt)
#pragma unroll
        for (int nt = 0; nt < 4; ++nt)
          acc[mt][nt] = __builtin_amdgcn_mfma_f32_16x16x32_bf16(af[mt], bf[nt], acc[mt][nt], 0, 0, 0);
    }
    __syncthreads();
  }
}

// ---------------- QKV projection + scatter ----------------
__global__ __launch_bounds__(256) void k_qkv_gemm(
    const unsigned short* __restrict__ xb, const unsigned short* __restrict__ wq,
    unsigned short* __restrict__ Q, unsigned short* __restrict__ Kc,
    unsigned short* __restrict__ Vt) {
  __shared__ __align__(16) unsigned short lds[2 * 128 * 64];
  f32x4 acc[4][4];
  const f32x4 fz = {0.f, 0.f, 0.f, 0.f};
#pragma unroll
  for (int i = 0; i < 4; ++i)
#pragma unroll
    for (int j = 0; j < 4; ++j) acc[i][j] = fz;

  const int m0 = blockIdx.x * 128, n0 = blockIdx.y * 128;
  gemm_bt_core(xb, wq, 1024, m0, n0, lds, lds + 128 * 64, acc);

  const int tid = threadIdx.x, wv = tid >> 6, lane = tid & 63;
  const int wm = (wv >> 1) << 6, wn = (wv & 1) << 6;
  const int r4 = (lane >> 4) << 2, fr = lane & 15;
#pragma unroll
  for (int mt = 0; mt < 4; ++mt)
#pragma unroll
    for (int nt = 0; nt < 4; ++nt) {
      const int row0 = m0 + wm + mt * 16 + r4;   // 4-row group, never straddles b
      const int col  = n0 + wn + nt * 16 + fr;   // n in [0,3072)
      const int b = row0 >> 11;
      const int which = col >> 10, rem = col & 1023;
      const int h = rem >> 6, hd = rem & 63;
      const size_t bh = (size_t)(b * 16 + h);
      if (which == 2) {
        const size_t vb = (bh * 64 + hd) * 2048 + (row0 & 2047);
        *(unsigned int*)&Vt[vb]     = pack2(acc[mt][nt][0], acc[mt][nt][1]);
        *(unsigned int*)&Vt[vb + 2] = pack2(acc[mt][nt][2], acc[mt][nt][3]);
      } else {
#pragma unroll
        for (int i = 0; i < 4; ++i) {
          const int lq = (row0 + i) & 2047;
          float v = acc[mt][nt][i];
          if (which == 0) Q [(bh * 2048 + lq) * 64 + hd] = f2b(v * 0.125f);
          else            Kc[(bh * 2048 + lq) * 64 + hd] = f2b(v);
        }
      }
    }
}

// ---------------- causal flash attention (LDS-shared K/V + defer-max) ----------------
// r16-PASSING structure; softmax common path = r7-validated defer-max (T13):
// per-lane pmax; if !__all(pmax-m_i<=8) do full reduce+rescale (rare), else keep m_i.
// lp accumulates per-lane, reduced once in the epilogue (r7-validated).
__global__ __launch_bounds__(256, 4) void k_attn(
    const unsigned short* __restrict__ Q, const unsigned short* __restrict__ Kc,
    const unsigned short* __restrict__ Vt, unsigned short* __restrict__ attn) {
  __shared__ __align__(16) unsigned short kbuf[2][32 * 64];   // 4KB per buf
  __shared__ __align__(16) unsigned short vbuf[2][64 * 32];   // 4KB per buf

  const int bh  = blockIdx.x & 31;
  const int grp = 31 - (blockIdx.x >> 5);      // 0..31, longest first
  const int wv = threadIdx.x >> 6, lane = threadIdx.x & 63;
  const int tid = threadIdx.x;
  const int strip = (grp << 2) + wv;           // 0..127
  const int qw = strip << 4;
  const int b = bh >> 4, h = bh & 15;
  const unsigned short* Qb = Q  + (size_t)bh * 2048 * 64;
  const unsigned short* Kb = Kc + (size_t)bh * 2048 * 64;
  const unsigned short* Vb = Vt + (size_t)bh * 64 * 2048;
  const int fr = lane & 15, g = lane >> 4;
  const int fk = g << 3, r4 = g << 2;
  const f32x4 fz = {0.f, 0.f, 0.f, 0.f};
  const bool godd = (g & 1) != 0;
  const bool gup  = g >= 2;
  const bool gswap = godd != gup;              // g==1 || g==2
  const int vswz = (fr & 3) ^ ((fr >> 2) & 3); // V read-granule swizzle

  const int ksrow = tid >> 3, kslog = (tid & 7) ^ (ksrow & 7);
  const int vsrow = tid >> 2, vslog = (tid & 3) ^ ((vsrow & 3) ^ ((vsrow >> 2) & 3));

  sh8 qf[2];
#pragma unroll
  for (int ks = 0; ks < 2; ++ks)
    qf[ks] = *(const sh8*)&Qb[(size_t)(qw + fr) * 64 + ks * 32 + fk];

  f32x4 o[4];
#pragma unroll
  for (int i = 0; i < 4; ++i) o[i] = fz;
  float m_i = -1e30f, lp = 0.f;

  const int njw = (qw + 47) >> 5;              // this wave's tiles (incl. diagonal)
  const int njm = ((grp << 6) + 95) >> 5;      // block max (longest strip)

  gload_lds16(&Kb[(size_t)ksrow * 64 + kslog * 8], &kbuf[0][tid * 8]);
  gload_lds16(&Vb[(size_t)vsrow * 2048 + vslog * 8], &vbuf[0][tid * 8]);

  for (int j = 0; j < njm; ++j) {
    __syncthreads();   // stage(j) complete (vmcnt drain); compute(j-1) done
    if (j + 1 < njm) {
      const int kvn = (j + 1) << 5;
      const int nb = (j + 1) & 1;
      gload_lds16(&Kb[(size_t)(kvn + ksrow) * 64 + kslog * 8], &kbuf[nb][tid * 8]);
      gload_lds16(&Vb[(size_t)vsrow * 2048 + kvn + vslog * 8], &vbuf[nb][tid * 8]);
    }
    if (j < njw) {
      const int kvb = j << 5;
      const unsigned short* kb = kbuf[j & 1];
      const unsigned short* vb = vbuf[j & 1];
      f32x4 s[2]; s[0] = fz; s[1] = fz;
#pragma unroll
      for (int t = 0; t < 2; ++t)
#pragma unroll
        for (int ks = 0; ks < 2; ++ks) {
          sh8 kf = *(const sh8*)&kb[(t * 16 + fr) * 64 + ((((ks << 2) + g) ^ (fr & 7)) << 3)];
          s[t] = __builtin_amdgcn_mfma_f32_16x16x32_bf16(kf, qf[ks], s[t], 0, 0, 0);
        }
      sh8 vf[4];
#pragma unroll
      for (int hb = 0; hb < 4; ++hb)
        vf[hb] = *(const sh8*)&vb[(hb * 16 + fr) * 32 + ((g ^ vswz) << 3)];

      if (j == njw - 1) {  // diagonal tile: causal mask (kv > q)
#pragma unroll
        for (int t = 0; t < 2; ++t)
#pragma unroll
          for (int i = 0; i < 4; ++i)
            if (kvb + t * 16 + r4 + i > qw + fr) s[t][i] = -1e30f;
      }
      // defer-max (T13, r7-validated): common path has NO cross-lane ops
      float pm = fmaxf(fmaxf(fmaxf(s[0][0], s[0][1]), fmaxf(s[0][2], s[0][3])),
                       fmaxf(fmaxf(s[1][0], s[1][1]), fmaxf(s[1][2], s[1][3])));
      if (!__all(pm - m_i <= 8.0f)) {   // rare: full row-max reduce + rescale
        float rm = fmaxf(pm, __shfl_xor(pm, 16, 64));
        rm = fmaxf(rm, __shfl_xor(rm, 32, 64));
        const float mn = fmaxf(m_i, rm);
        const float sc = __expf(m_i - mn);
        m_i = mn;
        lp *= sc;
#pragma unroll
        for (int hb = 0; hb < 4; ++hb)
#pragma unroll
          for (int i = 0; i < 4; ++i) o[hb][i] *= sc;
      }
      float p0[4], p1[4];
#pragma unroll
      for (int i = 0; i < 4; ++i) {
        p0[i] = __expf(s[0][i] - m_i);
        p1[i] = __expf(s[1][i] - m_i);
      }
      lp += ((p0[0] + p0[1]) + (p0[2] + p0[3])) + ((p1[0] + p1[1]) + (p1[2] + p1[3]));

      unsigned int P0L = pack2(p0[0], p0[1]);
      unsigned int P0H = pack2(p0[2], p0[3]);
      unsigned int P1L = pack2(p1[0], p1[1]);
      unsigned int P1H = pack2(p1[2], p1[3]);
      unsigned int x0 = __shfl_xor((int)P0L, 16, 64);
      unsigned int x1 = __shfl_xor((int)P0H, 16, 64);
      unsigned int y0 = __shfl_xor((int)P1L, 16, 64);
      unsigned int y1 = __shfl_xor((int)P1H, 16, 64);
      unsigned int A0 = godd ? x0 : P0L, A1 = godd ? x1 : P0H;
      unsigned int A2 = godd ? P0L : x0, A3 = godd ? P0H : x1;
      unsigned int B0 = godd ? y0 : P1L, B1 = godd ? y1 : P1H;
      unsigned int B2 = godd ? P1L : y0, B3 = godd ? P1H : y1;
      unsigned int As0 = __shfl_xor((int)A0, 32, 64), As1 = __shfl_xor((int)A1, 32, 64);
      unsigned int As2 = __shfl_xor((int)A2, 32, 64), As3 = __shfl_xor((int)A3, 32, 64);
      unsigned int Bs0 = __shfl_xor((int)B0, 32, 64), Bs1 = __shfl_xor((int)B1, 32, 64);
      unsigned int Bs2 = __shfl_xor((int)B2, 32, 64), Bs3 = __shfl_xor((int)B3, 32, 64);
      union { unsigned int w[4]; sh8 v; } fu;
      fu.w[0] = gswap ? (gup ? Bs0 : As0) : (gup ? B0 : A0);
      fu.w[1] = gswap ? (gup ? Bs1 : As1) : (gup ? B1 : A1);
      fu.w[2] = gswap ? (gup ? Bs2 : As2) : (gup ? B2 : A2);
      fu.w[3] = gswap ? (gup ? Bs3 : As3) : (gup ? B3 : A3);

#pragma unroll
      for (int hb = 0; hb < 4; ++hb)
        o[hb] = __builtin_amdgcn_mfma_f32_16x16x32_bf16(vf[hb], fu.v, o[hb], 0, 0, 0);
    }
  }

  // epilogue: reduce per-lane lp across the 4 g-groups once (r7-validated)
  float l = lp;
  l += __shfl_xor(l, 16, 64);
  l += __shfl_xor(l, 32, 64);
  const float inv = 1.0f / l;
  const size_t base = ((size_t)(b * 2048 + qw + fr)) * 1024 + h * 64;
#pragma unroll
  for (int hb = 0; hb < 4; ++hb)
#pragma unroll
    for (int i2 = 0; i2 < 2; ++i2) {
      unsigned int pw = pack2(o[hb][2 * i2] * inv, o[hb][2 * i2 + 1] * inv);
      *(unsigned int*)&attn[base + hb * 16 + r4 + 2 * i2] = pw;
    }
}

// ---------------- output projection + bias (fp32 out) ----------------
__global__ __launch_bounds__(256) void k_out_gemm(
    const unsigned short* __restrict__ attn, const unsigned short* __restrict__ wo,
    const float* __restrict__ bias, float* __restrict__ out) {
  __shared__ __align__(16) unsigned short lds[2 * 128 * 64];
  f32x4 acc[4][4];
  const f32x4 fz = {0.f, 0.f, 0.f, 0.f};
#pragma unroll
  for (int i = 0; i < 4; ++i)
#pragma unroll
    for (int j = 0; j < 4; ++j) acc[i][j] = fz;

  const int m0 = blockIdx.x * 128, n0 = blockIdx.y * 128;
  gemm_bt_core(attn, wo, 1024, m0, n0, lds, lds + 128 * 64, acc);

  const int tid = threadIdx.x, wv = tid >> 6, lane = tid & 63;
  const int wm = (wv >> 1) << 6, wn = (wv & 1) << 6;
  const int r4 = (lane >> 4) << 2, fr = lane & 15;
#pragma unroll
  for (int mt = 0; mt < 4; ++mt)
#pragma unroll
    for (int nt = 0; nt < 4; ++nt)
#pragma unroll
      for (int i = 0; i < 4; ++i) {
        int row = m0 + wm + mt * 16 + r4 + i;
        int col = n0 + wn + nt * 16 + fr;
        out[(size_t)row * 1024 + col] = acc[mt][nt][i] + bias[col];
      }
}

// ---------------- launch ----------------
extern "C" void kernel_launch(void* const* d_in, const int* in_sizes, int n_in,
                              void* d_out, int out_size, void* d_ws, size_t ws_size,
                              hipStream_t stream) {
  const float* x     = (const float*)d_in[0];
  const float* qkv_w = (const float*)d_in[1];
  const float* out_w = (const float*)d_in[2];
  const float* out_b = (const float*)d_in[3];
  float* out = (float*)d_out;

  unsigned short* ws   = (unsigned short*)d_ws;
  unsigned short* xb   = ws;                        // 4096*1024
  unsigned short* wq   = xb  + 4096 * 1024;         // 3072*1024
  unsigned short* wo   = wq  + 3072 * 1024;         // 1024*1024
  unsigned short* Qs   = wo  + 1024 * 1024;         // 32*2048*64
  unsigned short* Ks   = Qs  + 32 * 2048 * 64;      // 32*2048*64
  unsigned short* Vts  = Ks  + 32 * 2048 * 64;      // 32*64*2048
  unsigned short* attn = Vts + 32 * 64 * 2048;      // 4096*1024

  k_cvt<<<4096, 256, 0, stream>>>(x,     xb, 4096 * 1024);
  k_cvt<<<3072, 256, 0, stream>>>(qkv_w, wq, 3072 * 1024);
  k_cvt<<<1024, 256, 0, stream>>>(out_w, wo, 1024 * 1024);
  k_qkv_gemm<<<dim3(32, 24), 256, 0, stream>>>(xb, wq, Qs, Ks, Vts);
  k_attn<<<1024, 256, 0, stream>>>(Qs, Ks, Vts, attn);
  k_out_gemm<<<dim3(32, 8), 256, 0, stream>>>(attn, wo, out_b, out);
}

// Round 18
// 130.905 us; speedup vs baseline: 1.9344x; 1.0674x over previous
//
#include <hip/hip_runtime.h>
#include <hip/hip_bf16.h>
#include <cstdint>

// Toy MultiHeadAttention: B=2, L=2048, D=1024, H=16, HD=64, causal, eval (no dropout)
// Pipeline: fp32->bf16 converts; QKV GEMM (bf16 MFMA, T2-swizzled LDS) with Q/K/Vt
// scatter epilogue (Vt pack2); causal flash attention (r17-PASSING structure +
// defer-max + ZERO-SHUFFLE P->PV via 16x16x16 B-frag, r7/r8-validated math);
// out GEMM + bias (fp32 out).

typedef __attribute__((ext_vector_type(8))) short sh8;    // 8 bf16 (4 VGPRs) for 16x16x32
typedef __attribute__((ext_vector_type(4))) short sh4;    // 4 bf16 (2 VGPRs) for 16x16x16
typedef __attribute__((ext_vector_type(4))) float f32x4;  // MFMA C/D frag

__device__ __forceinline__ unsigned short f2b(float f) {  // fp32 -> bf16 RNE
  unsigned int u = __float_as_uint(f);
  u += 0x7FFFu + ((u >> 16) & 1u);
  return (unsigned short)(u >> 16);
}

__device__ __forceinline__ unsigned int pack2(float lo, float hi) {  // 2xbf16 in u32
  return (unsigned int)f2b(lo) | ((unsigned int)f2b(hi) << 16);
}

__device__ __forceinline__ f32x4 mfma16x16x16(sh4 a, sh4 b, f32x4 c) {
#if __has_builtin(__builtin_amdgcn_mfma_f32_16x16x16bf16_1k)
  return __builtin_amdgcn_mfma_f32_16x16x16bf16_1k(a, b, c, 0, 0, 0);
#else
  asm volatile("v_mfma_f32_16x16x16_bf16 %0, %1, %2, %0" : "+v"(c) : "v"(a), "v"(b));
  return c;
#endif
}

__device__ __forceinline__ void gload_lds16(const void* g, void* l) {
  __builtin_amdgcn_global_load_lds((__attribute__((address_space(1))) void*)g,
                                   (__attribute__((address_space(3))) void*)l,
                                   16, 0, 0);
}

// ---------------- fp32 -> bf16 convert (vectorized) ----------------
__global__ __launch_bounds__(256) void k_cvt(const float* __restrict__ in,
                                             unsigned short* __restrict__ out, int n) {
  int idx = (blockIdx.x * 256 + threadIdx.x) * 4;
  if (idx >= n) return;
  float4 v = *(const float4*)&in[idx];
  union { unsigned short u[4]; uint2 w; } r;
  r.u[0] = f2b(v.x); r.u[1] = f2b(v.y); r.u[2] = f2b(v.z); r.u[3] = f2b(v.w);
  *(uint2*)&out[idx] = r.w;
}

// ---------------- shared GEMM core: C[128x128] = A[M,K] * B[N,K]^T ----------------
// T2 XOR-swizzled LDS (r15/r16-validated): linear LDS dest for global_load_lds;
// GLOBAL source granule = (lane&7)^((lane>>3)&7); reads use slot ((ks*4+g)^(fr&7)).
__device__ __forceinline__ void gemm_bt_core(
    const unsigned short* __restrict__ A,   // [M][K] bf16 row-major
    const unsigned short* __restrict__ B,   // [N][K] bf16 row-major
    int K, int m0, int n0,
    unsigned short* ldsA, unsigned short* ldsB,
    f32x4 acc[4][4]) {
  const int tid  = threadIdx.x;
  const int wv   = tid >> 6;
  const int lane = tid & 63;
  const int wm = (wv >> 1) << 6;
  const int wn = (wv & 1) << 6;
  const int sr = (wv << 5) + (lane >> 3);
  const int sc  = (lane & 7) << 3;                          // linear LDS slot (dest)
  const int scg = (((lane & 7) ^ ((lane >> 3) & 7))) << 3;  // swizzled GLOBAL granule
  const int fr = lane & 15;
  const int g  = lane >> 4;

  for (int k0 = 0; k0 < K; k0 += 64) {
#pragma unroll
    for (int t = 0; t < 4; ++t) {
      int r = sr + (t << 3);
      gload_lds16(&A[(size_t)(m0 + r) * K + k0 + scg], &ldsA[r * 64 + sc]);
      gload_lds16(&B[(size_t)(n0 + r) * K + k0 + scg], &ldsB[r * 64 + sc]);
    }
    __syncthreads();
#pragma unroll
    for (int ks = 0; ks < 2; ++ks) {
      sh8 af[4], bf[4];
#pragma unroll
      for (int mt = 0; mt < 4; ++mt)
        af[mt] = *(const sh8*)&ldsA[(wm + mt * 16 + fr) * 64 +
                                    ((((ks << 2) + g) ^ (fr & 7)) << 3)];
#pragma unroll
      for (int nt = 0; nt < 4; ++nt)
        bf[nt] = *(const sh8*)&ldsB[(wn + nt * 16 + fr) * 64 +
                                    ((((ks << 2) + g) ^ (fr & 7)) << 3)];
#pragma unroll
      for (int mt = 0; mt < 4; ++mt)
#pragma unroll
        for (int nt = 0; nt < 4; ++nt)
          acc[mt][nt] = __builtin_amdgcn_mfma_f32_16x16x32_bf16(af[mt], bf[nt], acc[mt][nt], 0, 0, 0);
    }
    __syncthreads();
  }
}

// ---------------- QKV projection + scatter ----------------
__global__ __launch_bounds__(256) void k_qkv_gemm(
    const unsigned short* __restrict__ xb, const unsigned short* __restrict__ wq,
    unsigned short* __restrict__ Q, unsigned short* __restrict__ Kc,
    unsigned short* __restrict__ Vt) {
  __shared__ __align__(16) unsigned short lds[2 * 128 * 64];
  f32x4 acc[4][4];
  const f32x4 fz = {0.f, 0.f, 0.f, 0.f};
#pragma unroll
  for (int i = 0; i < 4; ++i)
#pragma unroll
    for (int j = 0; j < 4; ++j) acc[i][j] = fz;

  const int m0 = blockIdx.x * 128, n0 = blockIdx.y * 128;
  gemm_bt_core(xb, wq, 1024, m0, n0, lds, lds + 128 * 64, acc);

  const int tid = threadIdx.x, wv = tid >> 6, lane = tid & 63;
  const int wm = (wv >> 1) << 6, wn = (wv & 1) << 6;
  const int r4 = (lane >> 4) << 2, fr = lane & 15;
#pragma unroll
  for (int mt = 0; mt < 4; ++mt)
#pragma unroll
    for (int nt = 0; nt < 4; ++nt) {
      const int row0 = m0 + wm + mt * 16 + r4;   // 4-row group, never straddles b
      const int col  = n0 + wn + nt * 16 + fr;   // n in [0,3072)
      const int b = row0 >> 11;
      const int which = col >> 10, rem = col & 1023;
      const int h = rem >> 6, hd = rem & 63;
      const size_t bh = (size_t)(b * 16 + h);
      if (which == 2) {
        const size_t vb = (bh * 64 + hd) * 2048 + (row0 & 2047);
        *(unsigned int*)&Vt[vb]     = pack2(acc[mt][nt][0], acc[mt][nt][1]);
        *(unsigned int*)&Vt[vb + 2] = pack2(acc[mt][nt][2], acc[mt][nt][3]);
      } else {
#pragma unroll
        for (int i = 0; i < 4; ++i) {
          const int lq = (row0 + i) & 2047;
          float v = acc[mt][nt][i];
          if (which == 0) Q [(bh * 2048 + lq) * 64 + hd] = f2b(v * 0.125f);
          else            Kc[(bh * 2048 + lq) * 64 + hd] = f2b(v);
        }
      }
    }
}

// ---------------- causal flash attention ----------------
// r17-PASSING structure (LDS-shared K/V, defer-max T13) with the P^T register
// transpose ELIMINATED: swapped-QK^T's S^T layout (lane g,fr holds kv=4g+i at
// q=fr) IS the 16x16x16 B-frag layout (k=4g+j), so P packs straight into the PV
// B-operand (r7/r8-validated math). V read as sh4 pairs: granule (2t+(g>>1))^vswz,
// half-granule offset 4(g&1). PV = 8x mfma16x16x16.
__global__ __launch_bounds__(256, 4) void k_attn(
    const unsigned short* __restrict__ Q, const unsigned short* __restrict__ Kc,
    const unsigned short* __restrict__ Vt, unsigned short* __restrict__ attn) {
  __shared__ __align__(16) unsigned short kbuf[2][32 * 64];   // 4KB per buf
  __shared__ __align__(16) unsigned short vbuf[2][64 * 32];   // 4KB per buf

  const int bh  = blockIdx.x & 31;
  const int grp = 31 - (blockIdx.x >> 5);      // 0..31, longest first
  const int wv = threadIdx.x >> 6, lane = threadIdx.x & 63;
  const int tid = threadIdx.x;
  const int strip = (grp << 2) + wv;           // 0..127
  const int qw = strip << 4;
  const int b = bh >> 4, h = bh & 15;
  const unsigned short* Qb = Q  + (size_t)bh * 2048 * 64;
  const unsigned short* Kb = Kc + (size_t)bh * 2048 * 64;
  const unsigned short* Vb = Vt + (size_t)bh * 64 * 2048;
  const int fr = lane & 15, g = lane >> 4;
  const int fk = g << 3, r4 = g << 2;
  const f32x4 fz = {0.f, 0.f, 0.f, 0.f};
  const int vswz = (fr & 3) ^ ((fr >> 2) & 3); // V read-granule swizzle

  const int ksrow = tid >> 3, kslog = (tid & 7) ^ (ksrow & 7);
  const int vsrow = tid >> 2, vslog = (tid & 3) ^ ((vsrow & 3) ^ ((vsrow >> 2) & 3));

  sh8 qf[2];
#pragma unroll
  for (int ks = 0; ks < 2; ++ks)
    qf[ks] = *(const sh8*)&Qb[(size_t)(qw + fr) * 64 + ks * 32 + fk];

  f32x4 o[4];
#pragma unroll
  for (int i = 0; i < 4; ++i) o[i] = fz;
  float m_i = -1e30f, lp = 0.f;

  const int njw = (qw + 47) >> 5;              // this wave's tiles (incl. diagonal)
  const int njm = ((grp << 6) + 95) >> 5;      // block max (longest strip)

  gload_lds16(&Kb[(size_t)ksrow * 64 + kslog * 8], &kbuf[0][tid * 8]);
  gload_lds16(&Vb[(size_t)vsrow * 2048 + vslog * 8], &vbuf[0][tid * 8]);

  for (int j = 0; j < njm; ++j) {
    __syncthreads();   // stage(j) complete (vmcnt drain); compute(j-1) done
    if (j + 1 < njm) {
      const int kvn = (j + 1) << 5;
      const int nb = (j + 1) & 1;
      gload_lds16(&Kb[(size_t)(kvn + ksrow) * 64 + kslog * 8], &kbuf[nb][tid * 8]);
      gload_lds16(&Vb[(size_t)vsrow * 2048 + kvn + vslog * 8], &vbuf[nb][tid * 8]);
    }
    if (j < njw) {
      const int kvb = j << 5;
      const unsigned short* kb = kbuf[j & 1];
      const unsigned short* vb = vbuf[j & 1];
      f32x4 s[2]; s[0] = fz; s[1] = fz;
#pragma unroll
      for (int t = 0; t < 2; ++t)
#pragma unroll
        for (int ks = 0; ks < 2; ++ks) {
          sh8 kf = *(const sh8*)&kb[(t * 16 + fr) * 64 + ((((ks << 2) + g) ^ (fr & 7)) << 3)];
          s[t] = __builtin_amdgcn_mfma_f32_16x16x32_bf16(kf, qf[ks], s[t], 0, 0, 0);
        }
      // V frags for x16 PV (A-operand): row d = fr, k = 4g + jj, tile t
      sh4 vf[4][2];
#pragma unroll
      for (int hb = 0; hb < 4; ++hb)
#pragma unroll
        for (int t = 0; t < 2; ++t)
          vf[hb][t] = *(const sh4*)&vb[(hb * 16 + fr) * 32 +
                                       ((((t << 1) + (g >> 1)) ^ vswz) << 3) + ((g & 1) << 2)];

      if (j == njw - 1) {  // diagonal tile: causal mask (kv > q)
#pragma unroll
        for (int t = 0; t < 2; ++t)
#pragma unroll
          for (int i = 0; i < 4; ++i)
            if (kvb + t * 16 + r4 + i > qw + fr) s[t][i] = -1e30f;
      }
      // defer-max (T13, r7/r17-validated): common path has NO cross-lane ops
      float pm = fmaxf(fmaxf(fmaxf(s[0][0], s[0][1]), fmaxf(s[0][2], s[0][3])),
                       fmaxf(fmaxf(s[1][0], s[1][1]), fmaxf(s[1][2], s[1][3])));
      if (!__all(pm - m_i <= 8.0f)) {   // rare: full row-max reduce + rescale
        float rm = fmaxf(pm, __shfl_xor(pm, 16, 64));
        rm = fmaxf(rm, __shfl_xor(rm, 32, 64));
        const float mn = fmaxf(m_i, rm);
        const float sc = __expf(m_i - mn);
        m_i = mn;
        lp *= sc;
#pragma unroll
        for (int hb = 0; hb < 4; ++hb)
#pragma unroll
          for (int i = 0; i < 4; ++i) o[hb][i] *= sc;
      }
      float p0[4], p1[4];
#pragma unroll
      for (int i = 0; i < 4; ++i) {
        p0[i] = __expf(s[0][i] - m_i);
        p1[i] = __expf(s[1][i] - m_i);
      }
      lp += ((p0[0] + p0[1]) + (p0[2] + p0[3])) + ((p1[0] + p1[1]) + (p1[2] + p1[3]));

      // P already in x16 B-frag layout (col q=fr, k=4g+j): pack and feed PV directly
      union { unsigned int w[2]; sh4 v; } pb0, pb1;
      pb0.w[0] = pack2(p0[0], p0[1]); pb0.w[1] = pack2(p0[2], p0[3]);  // tile t=0
      pb1.w[0] = pack2(p1[0], p1[1]); pb1.w[1] = pack2(p1[2], p1[3]);  // tile t=1
#pragma unroll
      for (int hb = 0; hb < 4; ++hb) {
        o[hb] = mfma16x16x16(vf[hb][0], pb0.v, o[hb]);
        o[hb] = mfma16x16x16(vf[hb][1], pb1.v, o[hb]);
      }
    }
  }

  // epilogue: reduce per-lane lp across the 4 g-groups once (r7/r17-validated)
  float l = lp;
  l += __shfl_xor(l, 16, 64);
  l += __shfl_xor(l, 32, 64);
  const float inv = 1.0f / l;
  const size_t base = ((size_t)(b * 2048 + qw + fr)) * 1024 + h * 64;
#pragma unroll
  for (int hb = 0; hb < 4; ++hb)
#pragma unroll
    for (int i2 = 0; i2 < 2; ++i2) {
      unsigned int pw = pack2(o[hb][2 * i2] * inv, o[hb][2 * i2 + 1] * inv);
      *(unsigned int*)&attn[base + hb * 16 + r4 + 2 * i2] = pw;
    }
}

// ---------------- output projection + bias (fp32 out) ----------------
__global__ __launch_bounds__(256) void k_out_gemm(
    const unsigned short* __restrict__ attn, const unsigned short* __restrict__ wo,
    const float* __restrict__ bias, float* __restrict__ out) {
  __shared__ __align__(16) unsigned short lds[2 * 128 * 64];
  f32x4 acc[4][4];
  const f32x4 fz = {0.f, 0.f, 0.f, 0.f};
#pragma unroll
  for (int i = 0; i < 4; ++i)
#pragma unroll
    for (int j = 0; j < 4; ++j) acc[i][j] = fz;

  const int m0 = blockIdx.x * 128, n0 = blockIdx.y * 128;
  gemm_bt_core(attn, wo, 1024, m0, n0, lds, lds + 128 * 64, acc);

  const int tid = threadIdx.x, wv = tid >> 6, lane = tid & 63;
  const int wm = (wv >> 1) << 6, wn = (wv & 1) << 6;
  const int r4 = (lane >> 4) << 2, fr = lane & 15;
#pragma unroll
  for (int mt = 0; mt < 4; ++mt)
#pragma unroll
    for (int nt = 0; nt < 4; ++nt)
#pragma unroll
      for (int i = 0; i < 4; ++i) {
        int row = m0 + wm + mt * 16 + r4 + i;
        int col = n0 + wn + nt * 16 + fr;
        out[(size_t)row * 1024 + col] = acc[mt][nt][i] + bias[col];
      }
}

// ---------------- launch ----------------
extern "C" void kernel_launch(void* const* d_in, const int* in_sizes, int n_in,
                              void* d_out, int out_size, void* d_ws, size_t ws_size,
                              hipStream_t stream) {
  const float* x     = (const float*)d_in[0];
  const float* qkv_w = (const float*)d_in[1];
  const float* out_w = (const float*)d_in[2];
  const float* out_b = (const float*)d_in[3];
  float* out = (float*)d_out;

  unsigned short* ws   = (unsigned short*)d_ws;
  unsigned short* xb   = ws;                        // 4096*1024
  unsigned short* wq   = xb  + 4096 * 1024;         // 3072*1024
  unsigned short* wo   = wq  + 3072 * 1024;         // 1024*1024
  unsigned short* Qs   = wo  + 1024 * 1024;         // 32*2048*64
  unsigned short* Ks   = Qs  + 32 * 2048 * 64;      // 32*2048*64
  unsigned short* Vts  = Ks  + 32 * 2048 * 64;      // 32*64*2048
  unsigned short* attn = Vts + 32 * 64 * 2048;      // 4096*1024

  k_cvt<<<4096, 256, 0, stream>>>(x,     xb, 4096 * 1024);
  k_cvt<<<3072, 256, 0, stream>>>(qkv_w, wq, 3072 * 1024);
  k_cvt<<<1024, 256, 0, stream>>>(out_w, wo, 1024 * 1024);
  k_qkv_gemm<<<dim3(32, 24), 256, 0, stream>>>(xb, wq, Qs, Ks, Vts);
  k_attn<<<1024, 256, 0, stream>>>(Qs, Ks, Vts, attn);
  k_out_gemm<<<dim3(32, 8), 256, 0, stream>>>(attn, wo, out_b, out);
}

// Round 19
// 116.965 us; speedup vs baseline: 2.1649x; 1.1192x over previous
//
#include <hip/hip_runtime.h>
#include <hip/hip_bf16.h>
#include <cstdint>

// Toy MultiHeadAttention: B=2, L=2048, D=1024, H=16, HD=64, causal, eval (no dropout)
// Pipeline: fp32->bf16 converts; QKV GEMM (bf16 MFMA, T2-swizzled LDS, 64x128 tile
// for occupancy) with Q/K/Vt scatter epilogue; causal flash attention (r18-PASSING);
// out GEMM (64x64 tile) + bias (fp32 out).

typedef __attribute__((ext_vector_type(8))) short sh8;    // 8 bf16 (4 VGPRs) for 16x16x32
typedef __attribute__((ext_vector_type(4))) short sh4;    // 4 bf16 (2 VGPRs) for 16x16x16
typedef __attribute__((ext_vector_type(4))) float f32x4;  // MFMA C/D frag

__device__ __forceinline__ unsigned short f2b(float f) {  // fp32 -> bf16 RNE
  unsigned int u = __float_as_uint(f);
  u += 0x7FFFu + ((u >> 16) & 1u);
  return (unsigned short)(u >> 16);
}

__device__ __forceinline__ unsigned int pack2(float lo, float hi) {  // 2xbf16 in u32
  return (unsigned int)f2b(lo) | ((unsigned int)f2b(hi) << 16);
}

__device__ __forceinline__ f32x4 mfma16x16x16(sh4 a, sh4 b, f32x4 c) {
#if __has_builtin(__builtin_amdgcn_mfma_f32_16x16x16bf16_1k)
  return __builtin_amdgcn_mfma_f32_16x16x16bf16_1k(a, b, c, 0, 0, 0);
#else
  asm volatile("v_mfma_f32_16x16x16_bf16 %0, %1, %2, %0" : "+v"(c) : "v"(a), "v"(b));
  return c;
#endif
}

__device__ __forceinline__ void gload_lds16(const void* g, void* l) {
  __builtin_amdgcn_global_load_lds((__attribute__((address_space(1))) void*)g,
                                   (__attribute__((address_space(3))) void*)l,
                                   16, 0, 0);
}

// ---------------- fp32 -> bf16 convert (vectorized) ----------------
__global__ __launch_bounds__(256) void k_cvt(const float* __restrict__ in,
                                             unsigned short* __restrict__ out, int n) {
  int idx = (blockIdx.x * 256 + threadIdx.x) * 4;
  if (idx >= n) return;
  float4 v = *(const float4*)&in[idx];
  union { unsigned short u[4]; uint2 w; } r;
  r.u[0] = f2b(v.x); r.u[1] = f2b(v.y); r.u[2] = f2b(v.z); r.u[3] = f2b(v.w);
  *(uint2*)&out[idx] = r.w;
}

// ---------------- templated GEMM core: C[BM x BN] = A[M,K] * B[N,K]^T ----------------
// BM = MT*32, BN = NT*32; 256 thr = 4 waves in 2x2; wave owns (MT*16)x(NT*16).
// T2 XOR-swizzled LDS (r16/r18-validated): linear LDS dest for global_load_lds;
// GLOBAL source granule c^(r&7); fragment reads use slot ((ks*4+g)^(fr&7)).
template<int MT, int NT>
__device__ __forceinline__ void gemm_bt_core(
    const unsigned short* __restrict__ A,   // [M][K] bf16 row-major
    const unsigned short* __restrict__ B,   // [N][K] bf16 row-major
    int K, int m0, int n0,
    unsigned short* ldsA, unsigned short* ldsB,
    f32x4 acc[MT][NT]) {
  constexpr int TA = MT * 32 / 32;          // A granule-loads per thread
  constexpr int TB = NT * 32 / 32;          // B granule-loads per thread
  const int tid  = threadIdx.x;
  const int wv   = tid >> 6;
  const int lane = tid & 63;
  const int wm = (wv >> 1) * (MT * 16);
  const int wn = (wv & 1) * (NT * 16);
  const int fr = lane & 15;
  const int g  = lane >> 4;

  for (int k0 = 0; k0 < K; k0 += 64) {
#pragma unroll
    for (int t = 0; t < TA; ++t) {
      int gi = t * 256 + tid;               // granule index (wave-contiguous dest)
      int r = gi >> 3, c = gi & 7;
      gload_lds16(&A[(size_t)(m0 + r) * K + k0 + ((c ^ (r & 7)) << 3)], &ldsA[gi * 8]);
    }
#pragma unroll
    for (int t = 0; t < TB; ++t) {
      int gi = t * 256 + tid;
      int r = gi >> 3, c = gi & 7;
      gload_lds16(&B[(size_t)(n0 + r) * K + k0 + ((c ^ (r & 7)) << 3)], &ldsB[gi * 8]);
    }
    __syncthreads();
#pragma unroll
    for (int ks = 0; ks < 2; ++ks) {
      sh8 af[MT], bf[NT];
#pragma unroll
      for (int mt = 0; mt < MT; ++mt)
        af[mt] = *(const sh8*)&ldsA[(wm + mt * 16 + fr) * 64 +
                                    ((((ks << 2) + g) ^ (fr & 7)) << 3)];
#pragma unroll
      for (int nt = 0; nt < NT; ++nt)
        bf[nt] = *(const sh8*)&ldsB[(wn + nt * 16 + fr) * 64 +
                                    ((((ks << 2) + g) ^ (fr & 7)) << 3)];
#pragma unroll
      for (int mt = 0; mt < MT; ++mt)
#pragma unroll
        for (int nt = 0; nt < NT; ++nt)
          acc[mt][nt] = __builtin_amdgcn_mfma_f32_16x16x32_bf16(af[mt], bf[nt], acc[mt][nt], 0, 0, 0);
    }
    __syncthreads();
  }
}

// ---------------- QKV projection + scatter (BM=64, BN=128 -> 1536 blocks) ----------
__global__ __launch_bounds__(256, 5) void k_qkv_gemm(
    const unsigned short* __restrict__ xb, const unsigned short* __restrict__ wq,
    unsigned short* __restrict__ Q, unsigned short* __restrict__ Kc,
    unsigned short* __restrict__ Vt) {
  __shared__ __align__(16) unsigned short ldsA[64 * 64];    // 8KB
  __shared__ __align__(16) unsigned short ldsB[128 * 64];   // 16KB
  f32x4 acc[2][4];
  const f32x4 fz = {0.f, 0.f, 0.f, 0.f};
#pragma unroll
  for (int i = 0; i < 2; ++i)
#pragma unroll
    for (int j = 0; j < 4; ++j) acc[i][j] = fz;

  const int m0 = blockIdx.x * 64, n0 = blockIdx.y * 128;
  gemm_bt_core<2, 4>(xb, wq, 1024, m0, n0, ldsA, ldsB, acc);

  const int tid = threadIdx.x, wv = tid >> 6, lane = tid & 63;
  const int wm = (wv >> 1) << 5, wn = (wv & 1) << 6;
  const int r4 = (lane >> 4) << 2, fr = lane & 15;
#pragma unroll
  for (int mt = 0; mt < 2; ++mt)
#pragma unroll
    for (int nt = 0; nt < 4; ++nt) {
      const int row0 = m0 + wm + mt * 16 + r4;   // 4-row group, never straddles b
      const int col  = n0 + wn + nt * 16 + fr;   // n in [0,3072)
      const int b = row0 >> 11;
      const int which = col >> 10, rem = col & 1023;
      const int h = rem >> 6, hd = rem & 63;
      const size_t bh = (size_t)(b * 16 + h);
      if (which == 2) {
        const size_t vb = (bh * 64 + hd) * 2048 + (row0 & 2047);
        *(unsigned int*)&Vt[vb]     = pack2(acc[mt][nt][0], acc[mt][nt][1]);
        *(unsigned int*)&Vt[vb + 2] = pack2(acc[mt][nt][2], acc[mt][nt][3]);
      } else {
#pragma unroll
        for (int i = 0; i < 4; ++i) {
          const int lq = (row0 + i) & 2047;
          float v = acc[mt][nt][i];
          if (which == 0) Q [(bh * 2048 + lq) * 64 + hd] = f2b(v * 0.125f);
          else            Kc[(bh * 2048 + lq) * 64 + hd] = f2b(v);
        }
      }
    }
}

// ---------------- causal flash attention ----------------
// == UNCHANGED from round-18 PASSING kernel ==
__global__ __launch_bounds__(256, 4) void k_attn(
    const unsigned short* __restrict__ Q, const unsigned short* __restrict__ Kc,
    const unsigned short* __restrict__ Vt, unsigned short* __restrict__ attn) {
  __shared__ __align__(16) unsigned short kbuf[2][32 * 64];   // 4KB per buf
  __shared__ __align__(16) unsigned short vbuf[2][64 * 32];   // 4KB per buf

  const int bh  = blockIdx.x & 31;
  const int grp = 31 - (blockIdx.x >> 5);      // 0..31, longest first
  const int wv = threadIdx.x >> 6, lane = threadIdx.x & 63;
  const int tid = threadIdx.x;
  const int strip = (grp << 2) + wv;           // 0..127
  const int qw = strip << 4;
  const int b = bh >> 4, h = bh & 15;
  const unsigned short* Qb = Q  + (size_t)bh * 2048 * 64;
  const unsigned short* Kb = Kc + (size_t)bh * 2048 * 64;
  const unsigned short* Vb = Vt + (size_t)bh * 64 * 2048;
  const int fr = lane & 15, g = lane >> 4;
  const int fk = g << 3, r4 = g << 2;
  const f32x4 fz = {0.f, 0.f, 0.f, 0.f};
  const int vswz = (fr & 3) ^ ((fr >> 2) & 3); // V read-granule swizzle

  const int ksrow = tid >> 3, kslog = (tid & 7) ^ (ksrow & 7);
  const int vsrow = tid >> 2, vslog = (tid & 3) ^ ((vsrow & 3) ^ ((vsrow >> 2) & 3));

  sh8 qf[2];
#pragma unroll
  for (int ks = 0; ks < 2; ++ks)
    qf[ks] = *(const sh8*)&Qb[(size_t)(qw + fr) * 64 + ks * 32 + fk];

  f32x4 o[4];
#pragma unroll
  for (int i = 0; i < 4; ++i) o[i] = fz;
  float m_i = -1e30f, lp = 0.f;

  const int njw = (qw + 47) >> 5;              // this wave's tiles (incl. diagonal)
  const int njm = ((grp << 6) + 95) >> 5;      // block max (longest strip)

  gload_lds16(&Kb[(size_t)ksrow * 64 + kslog * 8], &kbuf[0][tid * 8]);
  gload_lds16(&Vb[(size_t)vsrow * 2048 + vslog * 8], &vbuf[0][tid * 8]);

  for (int j = 0; j < njm; ++j) {
    __syncthreads();   // stage(j) complete (vmcnt drain); compute(j-1) done
    if (j + 1 < njm) {
      const int kvn = (j + 1) << 5;
      const int nb = (j + 1) & 1;
      gload_lds16(&Kb[(size_t)(kvn + ksrow) * 64 + kslog * 8], &kbuf[nb][tid * 8]);
      gload_lds16(&Vb[(size_t)vsrow * 2048 + kvn + vslog * 8], &vbuf[nb][tid * 8]);
    }
    if (j < njw) {
      const int kvb = j << 5;
      const unsigned short* kb = kbuf[j & 1];
      const unsigned short* vb = vbuf[j & 1];
      f32x4 s[2]; s[0] = fz; s[1] = fz;
#pragma unroll
      for (int t = 0; t < 2; ++t)
#pragma unroll
        for (int ks = 0; ks < 2; ++ks) {
          sh8 kf = *(const sh8*)&kb[(t * 16 + fr) * 64 + ((((ks << 2) + g) ^ (fr & 7)) << 3)];
          s[t] = __builtin_amdgcn_mfma_f32_16x16x32_bf16(kf, qf[ks], s[t], 0, 0, 0);
        }
      // V frags for x16 PV (A-operand): row d = fr, k = 4g + jj, tile t
      sh4 vf[4][2];
#pragma unroll
      for (int hb = 0; hb < 4; ++hb)
#pragma unroll
        for (int t = 0; t < 2; ++t)
          vf[hb][t] = *(const sh4*)&vb[(hb * 16 + fr) * 32 +
                                       ((((t << 1) + (g >> 1)) ^ vswz) << 3) + ((g & 1) << 2)];

      if (j == njw - 1) {  // diagonal tile: causal mask (kv > q)
#pragma unroll
        for (int t = 0; t < 2; ++t)
#pragma unroll
          for (int i = 0; i < 4; ++i)
            if (kvb + t * 16 + r4 + i > qw + fr) s[t][i] = -1e30f;
      }
      // defer-max (T13, r7/r17-validated): common path has NO cross-lane ops
      float pm = fmaxf(fmaxf(fmaxf(s[0][0], s[0][1]), fmaxf(s[0][2], s[0][3])),
                       fmaxf(fmaxf(s[1][0], s[1][1]), fmaxf(s[1][2], s[1][3])));
      if (!__all(pm - m_i <= 8.0f)) {   // rare: full row-max reduce + rescale
        float rm = fmaxf(pm, __shfl_xor(pm, 16, 64));
        rm = fmaxf(rm, __shfl_xor(rm, 32, 64));
        const float mn = fmaxf(m_i, rm);
        const float sc = __expf(m_i - mn);
        m_i = mn;
        lp *= sc;
#pragma unroll
        for (int hb = 0; hb < 4; ++hb)
#pragma unroll
          for (int i = 0; i < 4; ++i) o[hb][i] *= sc;
      }
      float p0[4], p1[4];
#pragma unroll
      for (int i = 0; i < 4; ++i) {
        p0[i] = __expf(s[0][i] - m_i);
        p1[i] = __expf(s[1][i] - m_i);
      }
      lp += ((p0[0] + p0[1]) + (p0[2] + p0[3])) + ((p1[0] + p1[1]) + (p1[2] + p1[3]));

      // P already in x16 B-frag layout (col q=fr, k=4g+j): pack and feed PV directly
      union { unsigned int w[2]; sh4 v; } pb0, pb1;
      pb0.w[0] = pack2(p0[0], p0[1]); pb0.w[1] = pack2(p0[2], p0[3]);  // tile t=0
      pb1.w[0] = pack2(p1[0], p1[1]); pb1.w[1] = pack2(p1[2], p1[3]);  // tile t=1
#pragma unroll
      for (int hb = 0; hb < 4; ++hb) {
        o[hb] = mfma16x16x16(vf[hb][0], pb0.v, o[hb]);
        o[hb] = mfma16x16x16(vf[hb][1], pb1.v, o[hb]);
      }
    }
  }

  // epilogue: reduce per-lane lp across the 4 g-groups once (r7/r17-validated)
  float l = lp;
  l += __shfl_xor(l, 16, 64);
  l += __shfl_xor(l, 32, 64);
  const float inv = 1.0f / l;
  const size_t base = ((size_t)(b * 2048 + qw + fr)) * 1024 + h * 64;
#pragma unroll
  for (int hb = 0; hb < 4; ++hb)
#pragma unroll
    for (int i2 = 0; i2 < 2; ++i2) {
      unsigned int pw = pack2(o[hb][2 * i2] * inv, o[hb][2 * i2 + 1] * inv);
      *(unsigned int*)&attn[base + hb * 16 + r4 + 2 * i2] = pw;
    }
}

// ---------------- output projection + bias (BM=64, BN=64 -> 1024 blocks) ----------
__global__ __launch_bounds__(256, 5) void k_out_gemm(
    const unsigned short* __restrict__ attn, const unsigned short* __restrict__ wo,
    const float* __restrict__ bias, float* __restrict__ out) {
  __shared__ __align__(16) unsigned short ldsA[64 * 64];    // 8KB
  __shared__ __align__(16) unsigned short ldsB[64 * 64];    // 8KB
  f32x4 acc[2][2];
  const f32x4 fz = {0.f, 0.f, 0.f, 0.f};
#pragma unroll
  for (int i = 0; i < 2; ++i)
#pragma unroll
    for (int j = 0; j < 2; ++j) acc[i][j] = fz;

  const int m0 = blockIdx.x * 64, n0 = blockIdx.y * 64;
  gemm_bt_core<2, 2>(attn, wo, 1024, m0, n0, ldsA, ldsB, acc);

  const int tid = threadIdx.x, wv = tid >> 6, lane = tid & 63;
  const int wm = (wv >> 1) << 5, wn = (wv & 1) << 5;
  const int r4 = (lane >> 4) << 2, fr = lane & 15;
#pragma unroll
  for (int mt = 0; mt < 2; ++mt)
#pragma unroll
    for (int nt = 0; nt < 2; ++nt)
#pragma unroll
      for (int i = 0; i < 4; ++i) {
        int row = m0 + wm + mt * 16 + r4 + i;
        int col = n0 + wn + nt * 16 + fr;
        out[(size_t)row * 1024 + col] = acc[mt][nt][i] + bias[col];
      }
}

// ---------------- launch ----------------
extern "C" void kernel_launch(void* const* d_in, const int* in_sizes, int n_in,
                              void* d_out, int out_size, void* d_ws, size_t ws_size,
                              hipStream_t stream) {
  const float* x     = (const float*)d_in[0];
  const float* qkv_w = (const float*)d_in[1];
  const float* out_w = (const float*)d_in[2];
  const float* out_b = (const float*)d_in[3];
  float* out = (float*)d_out;

  unsigned short* ws   = (unsigned short*)d_ws;
  unsigned short* xb   = ws;                        // 4096*1024
  unsigned short* wq   = xb  + 4096 * 1024;         // 3072*1024
  unsigned short* wo   = wq  + 3072 * 1024;         // 1024*1024
  unsigned short* Qs   = wo  + 1024 * 1024;         // 32*2048*64
  unsigned short* Ks   = Qs  + 32 * 2048 * 64;      // 32*2048*64
  unsigned short* Vts  = Ks  + 32 * 2048 * 64;      // 32*64*2048
  unsigned short* attn = Vts + 32 * 64 * 2048;      // 4096*1024

  k_cvt<<<4096, 256, 0, stream>>>(x,     xb, 4096 * 1024);
  k_cvt<<<3072, 256, 0, stream>>>(qkv_w, wq, 3072 * 1024);
  k_cvt<<<1024, 256, 0, stream>>>(out_w, wo, 1024 * 1024);
  k_qkv_gemm<<<dim3(64, 24), 256, 0, stream>>>(xb, wq, Qs, Ks, Vts);
  k_attn<<<1024, 256, 0, stream>>>(Qs, Ks, Vts, attn);
  k_out_gemm<<<dim3(64, 16), 256, 0, stream>>>(attn, wo, out_b, out);
}

// Round 20
// 106.501 us; speedup vs baseline: 2.3777x; 1.0983x over previous
//
#include <hip/hip_runtime.h>
#include <hip/hip_bf16.h>
#include <cstdint>

// Toy MultiHeadAttention: B=2, L=2048, D=1024, H=16, HD=64, causal, eval (no dropout)
// Pipeline: fp32->bf16 converts; QKV GEMM (bf16 MFMA, T2-swizzled LDS, 64x128 tile);
// causal flash attention (KVBLK=64 LDS-shared K/V, defer-max, zero-shuffle x16 PV);
// out GEMM (64x64 tile) + bias (fp32 out).

typedef __attribute__((ext_vector_type(8))) short sh8;    // 8 bf16 (4 VGPRs) for 16x16x32
typedef __attribute__((ext_vector_type(4))) short sh4;    // 4 bf16 (2 VGPRs) for 16x16x16
typedef __attribute__((ext_vector_type(4))) float f32x4;  // MFMA C/D frag

__device__ __forceinline__ unsigned short f2b(float f) {  // fp32 -> bf16 RNE
  unsigned int u = __float_as_uint(f);
  u += 0x7FFFu + ((u >> 16) & 1u);
  return (unsigned short)(u >> 16);
}

__device__ __forceinline__ unsigned int pack2(float lo, float hi) {  // 2xbf16 in u32
  return (unsigned int)f2b(lo) | ((unsigned int)f2b(hi) << 16);
}

__device__ __forceinline__ f32x4 mfma16x16x16(sh4 a, sh4 b, f32x4 c) {
#if __has_builtin(__builtin_amdgcn_mfma_f32_16x16x16bf16_1k)
  return __builtin_amdgcn_mfma_f32_16x16x16bf16_1k(a, b, c, 0, 0, 0);
#else
  asm volatile("v_mfma_f32_16x16x16_bf16 %0, %1, %2, %0" : "+v"(c) : "v"(a), "v"(b));
  return c;
#endif
}

__device__ __forceinline__ void gload_lds16(const void* g, void* l) {
  __builtin_amdgcn_global_load_lds((__attribute__((address_space(1))) void*)g,
                                   (__attribute__((address_space(3))) void*)l,
                                   16, 0, 0);
}

// ---------------- fp32 -> bf16 convert (vectorized) ----------------
__global__ __launch_bounds__(256) void k_cvt(const float* __restrict__ in,
                                             unsigned short* __restrict__ out, int n) {
  int idx = (blockIdx.x * 256 + threadIdx.x) * 4;
  if (idx >= n) return;
  float4 v = *(const float4*)&in[idx];
  union { unsigned short u[4]; uint2 w; } r;
  r.u[0] = f2b(v.x); r.u[1] = f2b(v.y); r.u[2] = f2b(v.z); r.u[3] = f2b(v.w);
  *(uint2*)&out[idx] = r.w;
}

// ---------------- templated GEMM core: C[BM x BN] = A[M,K] * B[N,K]^T ----------------
// BM = MT*32, BN = NT*32; 256 thr = 4 waves in 2x2; wave owns (MT*16)x(NT*16).
// T2 XOR-swizzled LDS (r16/r18/r19-validated).
template<int MT, int NT>
__device__ __forceinline__ void gemm_bt_core(
    const unsigned short* __restrict__ A,   // [M][K] bf16 row-major
    const unsigned short* __restrict__ B,   // [N][K] bf16 row-major
    int K, int m0, int n0,
    unsigned short* ldsA, unsigned short* ldsB,
    f32x4 acc[MT][NT]) {
  constexpr int TA = MT;          // A granule-loads per thread (MT*32 rows * 8 / 256)
  constexpr int TB = NT;
  const int tid  = threadIdx.x;
  const int wv   = tid >> 6;
  const int lane = tid & 63;
  const int wm = (wv >> 1) * (MT * 16);
  const int wn = (wv & 1) * (NT * 16);
  const int fr = lane & 15;
  const int g  = lane >> 4;

  for (int k0 = 0; k0 < K; k0 += 64) {
#pragma unroll
    for (int t = 0; t < TA; ++t) {
      int gi = t * 256 + tid;               // granule index (wave-contiguous dest)
      int r = gi >> 3, c = gi & 7;
      gload_lds16(&A[(size_t)(m0 + r) * K + k0 + ((c ^ (r & 7)) << 3)], &ldsA[gi * 8]);
    }
#pragma unroll
    for (int t = 0; t < TB; ++t) {
      int gi = t * 256 + tid;
      int r = gi >> 3, c = gi & 7;
      gload_lds16(&B[(size_t)(n0 + r) * K + k0 + ((c ^ (r & 7)) << 3)], &ldsB[gi * 8]);
    }
    __syncthreads();
#pragma unroll
    for (int ks = 0; ks < 2; ++ks) {
      sh8 af[MT], bf[NT];
#pragma unroll
      for (int mt = 0; mt < MT; ++mt)
        af[mt] = *(const sh8*)&ldsA[(wm + mt * 16 + fr) * 64 +
                                    ((((ks << 2) + g) ^ (fr & 7)) << 3)];
#pragma unroll
      for (int nt = 0; nt < NT; ++nt)
        bf[nt] = *(const sh8*)&ldsB[(wn + nt * 16 + fr) * 64 +
                                    ((((ks << 2) + g) ^ (fr & 7)) << 3)];
#pragma unroll
      for (int mt = 0; mt < MT; ++mt)
#pragma unroll
        for (int nt = 0; nt < NT; ++nt)
          acc[mt][nt] = __builtin_amdgcn_mfma_f32_16x16x32_bf16(af[mt], bf[nt], acc[mt][nt], 0, 0, 0);
    }
    __syncthreads();
  }
}

// ---------------- QKV projection + scatter (BM=64, BN=128 -> 1536 blocks) ----------
__global__ __launch_bounds__(256, 5) void k_qkv_gemm(
    const unsigned short* __restrict__ xb, const unsigned short* __restrict__ wq,
    unsigned short* __restrict__ Q, unsigned short* __restrict__ Kc,
    unsigned short* __restrict__ Vt) {
  __shared__ __align__(16) unsigned short ldsA[64 * 64];    // 8KB
  __shared__ __align__(16) unsigned short ldsB[128 * 64];   // 16KB
  f32x4 acc[2][4];
  const f32x4 fz = {0.f, 0.f, 0.f, 0.f};
#pragma unroll
  for (int i = 0; i < 2; ++i)
#pragma unroll
    for (int j = 0; j < 4; ++j) acc[i][j] = fz;

  const int m0 = blockIdx.x * 64, n0 = blockIdx.y * 128;
  gemm_bt_core<2, 4>(xb, wq, 1024, m0, n0, ldsA, ldsB, acc);

  const int tid = threadIdx.x, wv = tid >> 6, lane = tid & 63;
  const int wm = (wv >> 1) << 5, wn = (wv & 1) << 6;
  const int r4 = (lane >> 4) << 2, fr = lane & 15;
#pragma unroll
  for (int mt = 0; mt < 2; ++mt)
#pragma unroll
    for (int nt = 0; nt < 4; ++nt) {
      const int row0 = m0 + wm + mt * 16 + r4;   // 4-row group, never straddles b
      const int col  = n0 + wn + nt * 16 + fr;   // n in [0,3072)
      const int b = row0 >> 11;
      const int which = col >> 10, rem = col & 1023;
      const int h = rem >> 6, hd = rem & 63;
      const size_t bh = (size_t)(b * 16 + h);
      if (which == 2) {
        const size_t vb = (bh * 64 + hd) * 2048 + (row0 & 2047);
        *(unsigned int*)&Vt[vb]     = pack2(acc[mt][nt][0], acc[mt][nt][1]);
        *(unsigned int*)&Vt[vb + 2] = pack2(acc[mt][nt][2], acc[mt][nt][3]);
      } else {
#pragma unroll
        for (int i = 0; i < 4; ++i) {
          const int lq = (row0 + i) & 2047;
          float v = acc[mt][nt][i];
          if (which == 0) Q [(bh * 2048 + lq) * 64 + hd] = f2b(v * 0.125f);
          else            Kc[(bh * 2048 + lq) * 64 + hd] = f2b(v);
        }
      }
    }
}

// ---------------- causal flash attention (KVBLK=64, LDS-shared K/V) ----------------
// grid: 1024 blocks x 256 thr; blockIdx = gIdx*32 + bh; grp = 31 - gIdx (longest
// first, bh fastest). Wave wv owns strip = grp*4 + wv; ALL waves have njw = grp+1
// tiles (uniform -- no idle waves). Per 64-kv tile: K(64x64)+V^T(64x64) staged into
// dbuf LDS (granule swizzle c^(r&7), r15/r16-validated form); 4 QK sub-tiles
// (s[4], independent MFMA chains); defer-max (T13); exp in place; zero-shuffle
// x16 PV per sub-tile. Softmax algebra byte-identical to r17/r18 (per q-col = fr).
__global__ __launch_bounds__(256, 4) void k_attn(
    const unsigned short* __restrict__ Q, const unsigned short* __restrict__ Kc,
    const unsigned short* __restrict__ Vt, unsigned short* __restrict__ attn) {
  __shared__ __align__(16) unsigned short kbuf[2][64 * 64];   // 8KB per buf
  __shared__ __align__(16) unsigned short vbuf[2][64 * 64];   // 8KB per buf

  const int bh  = blockIdx.x & 31;
  const int grp = 31 - (blockIdx.x >> 5);      // 0..31, longest first
  const int wv = threadIdx.x >> 6, lane = threadIdx.x & 63;
  const int tid = threadIdx.x;
  const int strip = (grp << 2) + wv;           // 0..127
  const int qw = strip << 4;
  const int b = bh >> 4, h = bh & 15;
  const unsigned short* Qb = Q  + (size_t)bh * 2048 * 64;
  const unsigned short* Kb = Kc + (size_t)bh * 2048 * 64;
  const unsigned short* Vb = Vt + (size_t)bh * 64 * 2048;
  const int fr = lane & 15, g = lane >> 4;
  const int fk = g << 3, r4 = g << 2;
  const f32x4 fz = {0.f, 0.f, 0.f, 0.f};

  // staging map: 512 granules per buffer, 2 per thread
  const int sgr0 = tid >> 3,        sgc0 = tid & 7;          // granule (row, col)
  const int sgr1 = (tid + 256) >> 3, sgc1 = tid & 7;         // second granule

  sh8 qf[2];
#pragma unroll
  for (int ks = 0; ks < 2; ++ks)
    qf[ks] = *(const sh8*)&Qb[(size_t)(qw + fr) * 64 + ks * 32 + fk];

  f32x4 o[4];
#pragma unroll
  for (int i = 0; i < 4; ++i) o[i] = fz;
  float m_i = -1e30f, lp = 0.f;

  const int njm = grp + 1;                     // uniform tile count (incl. diagonal)

  // stage tile 0 into buf 0
  gload_lds16(&Kb[(size_t)sgr0 * 64 + ((sgc0 ^ (sgr0 & 7)) << 3)], &kbuf[0][tid * 8]);
  gload_lds16(&Kb[(size_t)sgr1 * 64 + ((sgc1 ^ (sgr1 & 7)) << 3)], &kbuf[0][(tid + 256) * 8]);
  gload_lds16(&Vb[(size_t)sgr0 * 2048 + ((sgc0 ^ (sgr0 & 7)) << 3)], &vbuf[0][tid * 8]);
  gload_lds16(&Vb[(size_t)sgr1 * 2048 + ((sgc1 ^ (sgr1 & 7)) << 3)], &vbuf[0][(tid + 256) * 8]);

  for (int j = 0; j < njm; ++j) {
    __syncthreads();   // stage(j) complete (vmcnt drain); compute(j-1) done
    if (j + 1 < njm) {
      const int kvn = (j + 1) << 6;
      const int nb = (j + 1) & 1;
      gload_lds16(&Kb[(size_t)(kvn + sgr0) * 64 + ((sgc0 ^ (sgr0 & 7)) << 3)], &kbuf[nb][tid * 8]);
      gload_lds16(&Kb[(size_t)(kvn + sgr1) * 64 + ((sgc1 ^ (sgr1 & 7)) << 3)], &kbuf[nb][(tid + 256) * 8]);
      gload_lds16(&Vb[(size_t)sgr0 * 2048 + kvn + ((sgc0 ^ (sgr0 & 7)) << 3)], &vbuf[nb][tid * 8]);
      gload_lds16(&Vb[(size_t)sgr1 * 2048 + kvn + ((sgc1 ^ (sgr1 & 7)) << 3)], &vbuf[nb][(tid + 256) * 8]);
    }
    const int kvb = j << 6;
    const unsigned short* kb = kbuf[j & 1];
    const unsigned short* vb = vbuf[j & 1];
    // QK^T swapped, 4 independent sub-tiles: s[t] rows kv = kvb+16t+4g+i, col q = fr
    f32x4 s[4];
#pragma unroll
    for (int t = 0; t < 4; ++t) s[t] = fz;
#pragma unroll
    for (int ks = 0; ks < 2; ++ks)
#pragma unroll
      for (int t = 0; t < 4; ++t) {
        sh8 kf = *(const sh8*)&kb[(t * 16 + fr) * 64 + ((((ks << 2) + g) ^ (fr & 7)) << 3)];
        s[t] = __builtin_amdgcn_mfma_f32_16x16x32_bf16(kf, qf[ks], s[t], 0, 0, 0);
      }

    if (j == njm - 1) {  // diagonal tile: causal mask (kv > q)
#pragma unroll
      for (int t = 0; t < 4; ++t)
#pragma unroll
        for (int i = 0; i < 4; ++i)
          if (kvb + t * 16 + r4 + i > qw + fr) s[t][i] = -1e30f;
    }
    // defer-max (T13): common path has NO cross-lane ops
    float pm = s[0][0];
#pragma unroll
    for (int t = 0; t < 4; ++t)
#pragma unroll
      for (int i = 0; i < 4; ++i) pm = fmaxf(pm, s[t][i]);
    if (!__all(pm - m_i <= 8.0f)) {   // rare: full row-max reduce + rescale
      float rm = fmaxf(pm, __shfl_xor(pm, 16, 64));
      rm = fmaxf(rm, __shfl_xor(rm, 32, 64));
      const float mn = fmaxf(m_i, rm);
      const float sc = __expf(m_i - mn);
      m_i = mn;
      lp *= sc;
#pragma unroll
      for (int hb = 0; hb < 4; ++hb)
#pragma unroll
        for (int i = 0; i < 4; ++i) o[hb][i] *= sc;
    }
    // exp in place; lp per-lane partial
#pragma unroll
    for (int t = 0; t < 4; ++t) {
#pragma unroll
      for (int i = 0; i < 4; ++i) s[t][i] = __expf(s[t][i] - m_i);
      lp += (s[t][0] + s[t][1]) + (s[t][2] + s[t][3]);
    }
    // PV per sub-tile: P already in x16 B-frag layout (col q=fr, k=4g+j)
#pragma unroll
    for (int t = 0; t < 4; ++t) {
      union { unsigned int w[2]; sh4 v; } pb;
      pb.w[0] = pack2(s[t][0], s[t][1]);
      pb.w[1] = pack2(s[t][2], s[t][3]);
#pragma unroll
      for (int hb = 0; hb < 4; ++hb) {
        sh4 vf = *(const sh4*)&vb[(hb * 16 + fr) * 64 +
                                  ((((t << 1) + (g >> 1)) ^ (fr & 7)) << 3) + ((g & 1) << 2)];
        o[hb] = mfma16x16x16(vf, pb.v, o[hb]);
      }
    }
  }

  // epilogue: reduce per-lane lp across the 4 g-groups once (r7/r17-validated)
  float l = lp;
  l += __shfl_xor(l, 16, 64);
  l += __shfl_xor(l, 32, 64);
  const float inv = 1.0f / l;
  const size_t base = ((size_t)(b * 2048 + qw + fr)) * 1024 + h * 64;
#pragma unroll
  for (int hb = 0; hb < 4; ++hb)
#pragma unroll
    for (int i2 = 0; i2 < 2; ++i2) {
      unsigned int pw = pack2(o[hb][2 * i2] * inv, o[hb][2 * i2 + 1] * inv);
      *(unsigned int*)&attn[base + hb * 16 + r4 + 2 * i2] = pw;
    }
}

// ---------------- output projection + bias (BM=64, BN=64 -> 1024 blocks) ----------
__global__ __launch_bounds__(256, 5) void k_out_gemm(
    const unsigned short* __restrict__ attn, const unsigned short* __restrict__ wo,
    const float* __restrict__ bias, float* __restrict__ out) {
  __shared__ __align__(16) unsigned short ldsA[64 * 64];    // 8KB
  __shared__ __align__(16) unsigned short ldsB[64 * 64];    // 8KB
  f32x4 acc[2][2];
  const f32x4 fz = {0.f, 0.f, 0.f, 0.f};
#pragma unroll
  for (int i = 0; i < 2; ++i)
#pragma unroll
    for (int j = 0; j < 2; ++j) acc[i][j] = fz;

  const int m0 = blockIdx.x * 64, n0 = blockIdx.y * 64;
  gemm_bt_core<2, 2>(attn, wo, 1024, m0, n0, ldsA, ldsB, acc);

  const int tid = threadIdx.x, wv = tid >> 6, lane = tid & 63;
  const int wm = (wv >> 1) << 5, wn = (wv & 1) << 5;
  const int r4 = (lane >> 4) << 2, fr = lane & 15;
#pragma unroll
  for (int mt = 0; mt < 2; ++mt)
#pragma unroll
    for (int nt = 0; nt < 2; ++nt)
#pragma unroll
      for (int i = 0; i < 4; ++i) {
        int row = m0 + wm + mt * 16 + r4 + i;
        int col = n0 + wn + nt * 16 + fr;
        out[(size_t)row * 1024 + col] = acc[mt][nt][i] + bias[col];
      }
}

// ---------------- launch ----------------
extern "C" void kernel_launch(void* const* d_in, const int* in_sizes, int n_in,
                              void* d_out, int out_size, void* d_ws, size_t ws_size,
                              hipStream_t stream) {
  const float* x     = (const float*)d_in[0];
  const float* qkv_w = (const float*)d_in[1];
  const float* out_w = (const float*)d_in[2];
  const float* out_b = (const float*)d_in[3];
  float* out = (float*)d_out;

  unsigned short* ws   = (unsigned short*)d_ws;
  unsigned short* xb   = ws;                        // 4096*1024
  unsigned short* wq   = xb  + 4096 * 1024;         // 3072*1024
  unsigned short* wo   = wq  + 3072 * 1024;         // 1024*1024
  unsigned short* Qs   = wo  + 1024 * 1024;         // 32*2048*64
  unsigned short* Ks   = Qs  + 32 * 2048 * 64;      // 32*2048*64
  unsigned short* Vts  = Ks  + 32 * 2048 * 64;      // 32*64*2048
  unsigned short* attn = Vts + 32 * 64 * 2048;      // 4096*1024

  k_cvt<<<4096, 256, 0, stream>>>(x,     xb, 4096 * 1024);
  k_cvt<<<3072, 256, 0, stream>>>(qkv_w, wq, 3072 * 1024);
  k_cvt<<<1024, 256, 0, stream>>>(out_w, wo, 1024 * 1024);
  k_qkv_gemm<<<dim3(64, 24), 256, 0, stream>>>(xb, wq, Qs, Ks, Vts);
  k_attn<<<1024, 256, 0, stream>>>(Qs, Ks, Vts, attn);
  k_out_gemm<<<dim3(64, 16), 256, 0, stream>>>(attn, wo, out_b, out);
}

// Round 21
// 106.487 us; speedup vs baseline: 2.3780x; 1.0001x over previous
//
#include <hip/hip_runtime.h>
#include <hip/hip_bf16.h>
#include <cstdint>

// Toy MultiHeadAttention: B=2, L=2048, D=1024, H=16, HD=64, causal, eval (no dropout)
// Pipeline: fp32->bf16 converts; QKV GEMM (bf16 MFMA, T2-swizzled dbuf LDS, 64x128);
// causal flash attention (KVBLK=64 LDS-shared K/V, defer-max, zero-shuffle x16 PV);
// out GEMM (64x64, dbuf) + bias (fp32 out).

typedef __attribute__((ext_vector_type(8))) short sh8;    // 8 bf16 (4 VGPRs) for 16x16x32
typedef __attribute__((ext_vector_type(4))) short sh4;    // 4 bf16 (2 VGPRs) for 16x16x16
typedef __attribute__((ext_vector_type(4))) float f32x4;  // MFMA C/D frag

__device__ __forceinline__ unsigned short f2b(float f) {  // fp32 -> bf16 RNE
  unsigned int u = __float_as_uint(f);
  u += 0x7FFFu + ((u >> 16) & 1u);
  return (unsigned short)(u >> 16);
}

__device__ __forceinline__ unsigned int pack2(float lo, float hi) {  // 2xbf16 in u32
  return (unsigned int)f2b(lo) | ((unsigned int)f2b(hi) << 16);
}

__device__ __forceinline__ f32x4 mfma16x16x16(sh4 a, sh4 b, f32x4 c) {
#if __has_builtin(__builtin_amdgcn_mfma_f32_16x16x16bf16_1k)
  return __builtin_amdgcn_mfma_f32_16x16x16bf16_1k(a, b, c, 0, 0, 0);
#else
  asm volatile("v_mfma_f32_16x16x16_bf16 %0, %1, %2, %0" : "+v"(c) : "v"(a), "v"(b));
  return c;
#endif
}

__device__ __forceinline__ void gload_lds16(const void* g, void* l) {
  __builtin_amdgcn_global_load_lds((__attribute__((address_space(1))) void*)g,
                                   (__attribute__((address_space(3))) void*)l,
                                   16, 0, 0);
}

// ---------------- fp32 -> bf16 convert (vectorized) ----------------
__global__ __launch_bounds__(256) void k_cvt(const float* __restrict__ in,
                                             unsigned short* __restrict__ out, int n) {
  int idx = (blockIdx.x * 256 + threadIdx.x) * 4;
  if (idx >= n) return;
  float4 v = *(const float4*)&in[idx];
  union { unsigned short u[4]; uint2 w; } r;
  r.u[0] = f2b(v.x); r.u[1] = f2b(v.y); r.u[2] = f2b(v.z); r.u[3] = f2b(v.w);
  *(uint2*)&out[idx] = r.w;
}

// ---------------- templated GEMM core: C[BM x BN] = A[M,K] * B[N,K]^T ----------------
// BM = MT*32, BN = NT*32; 256 thr = 4 waves in 2x2; wave owns (MT*16)x(NT*16).
// T2 XOR-swizzled LDS (r16/r18/r19-validated) + SINGLE-BARRIER DBUF STAGING
// (attn-validated r15/r19/r20 pattern): prefetch K-step kk+1 into buf^1 right
// after the barrier, compute kk from buf; one barrier per K-step, staging
// latency hidden under compute. ldsA/ldsB are DOUBLE-size buffers.
template<int MT, int NT>
__device__ __forceinline__ void gemm_bt_core(
    const unsigned short* __restrict__ A,   // [M][K] bf16 row-major
    const unsigned short* __restrict__ B,   // [N][K] bf16 row-major
    int K, int m0, int n0,
    unsigned short* ldsA, unsigned short* ldsB,
    f32x4 acc[MT][NT]) {
  constexpr int ASZ = MT * 32 * 64;         // elements per A buffer
  constexpr int BSZ = NT * 32 * 64;
  const int tid  = threadIdx.x;
  const int wv   = tid >> 6;
  const int lane = tid & 63;
  const int wm = (wv >> 1) * (MT * 16);
  const int wn = (wv & 1) * (NT * 16);
  const int fr = lane & 15;
  const int g  = lane >> 4;

  auto stage = [&](int k0, unsigned short* dA, unsigned short* dB) {
#pragma unroll
    for (int t = 0; t < MT; ++t) {
      int gi = t * 256 + tid;               // granule index (wave-contiguous dest)
      int r = gi >> 3, c = gi & 7;
      gload_lds16(&A[(size_t)(m0 + r) * K + k0 + ((c ^ (r & 7)) << 3)], &dA[gi * 8]);
    }
#pragma unroll
    for (int t = 0; t < NT; ++t) {
      int gi = t * 256 + tid;
      int r = gi >> 3, c = gi & 7;
      gload_lds16(&B[(size_t)(n0 + r) * K + k0 + ((c ^ (r & 7)) << 3)], &dB[gi * 8]);
    }
  };

  const int nk = K >> 6;
  stage(0, ldsA, ldsB);
  for (int kk = 0; kk < nk; ++kk) {
    __syncthreads();   // stage(kk) complete (vmcnt drain); compute(kk-1) done
    if (kk + 1 < nk)
      stage((kk + 1) << 6, ldsA + ((kk + 1) & 1) * ASZ, ldsB + ((kk + 1) & 1) * BSZ);
    const unsigned short* a = ldsA + (kk & 1) * ASZ;
    const unsigned short* b = ldsB + (kk & 1) * BSZ;
#pragma unroll
    for (int ks = 0; ks < 2; ++ks) {
      sh8 af[MT], bf[NT];
#pragma unroll
      for (int mt = 0; mt < MT; ++mt)
        af[mt] = *(const sh8*)&a[(wm + mt * 16 + fr) * 64 +
                                 ((((ks << 2) + g) ^ (fr & 7)) << 3)];
#pragma unroll
      for (int nt = 0; nt < NT; ++nt)
        bf[nt] = *(const sh8*)&b[(wn + nt * 16 + fr) * 64 +
                                 ((((ks << 2) + g) ^ (fr & 7)) << 3)];
#pragma unroll
      for (int mt = 0; mt < MT; ++mt)
#pragma unroll
        for (int nt = 0; nt < NT; ++nt)
          acc[mt][nt] = __builtin_amdgcn_mfma_f32_16x16x32_bf16(af[mt], bf[nt], acc[mt][nt], 0, 0, 0);
    }
  }
}

// ---------------- QKV projection + scatter (BM=64, BN=128 -> 1536 blocks) ----------
__global__ __launch_bounds__(256, 3) void k_qkv_gemm(
    const unsigned short* __restrict__ xb, const unsigned short* __restrict__ wq,
    unsigned short* __restrict__ Q, unsigned short* __restrict__ Kc,
    unsigned short* __restrict__ Vt) {
  __shared__ __align__(16) unsigned short ldsA[2 * 64 * 64];    // 16KB (dbuf)
  __shared__ __align__(16) unsigned short ldsB[2 * 128 * 64];   // 32KB (dbuf)
  f32x4 acc[2][4];
  const f32x4 fz = {0.f, 0.f, 0.f, 0.f};
#pragma unroll
  for (int i = 0; i < 2; ++i)
#pragma unroll
    for (int j = 0; j < 4; ++j) acc[i][j] = fz;

  const int m0 = blockIdx.x * 64, n0 = blockIdx.y * 128;
  gemm_bt_core<2, 4>(xb, wq, 1024, m0, n0, ldsA, ldsB, acc);

  const int tid = threadIdx.x, wv = tid >> 6, lane = tid & 63;
  const int wm = (wv >> 1) << 5, wn = (wv & 1) << 6;
  const int r4 = (lane >> 4) << 2, fr = lane & 15;
#pragma unroll
  for (int mt = 0; mt < 2; ++mt)
#pragma unroll
    for (int nt = 0; nt < 4; ++nt) {
      const int row0 = m0 + wm + mt * 16 + r4;   // 4-row group, never straddles b
      const int col  = n0 + wn + nt * 16 + fr;   // n in [0,3072)
      const int b = row0 >> 11;
      const int which = col >> 10, rem = col & 1023;
      const int h = rem >> 6, hd = rem & 63;
      const size_t bh = (size_t)(b * 16 + h);
      if (which == 2) {
        const size_t vb = (bh * 64 + hd) * 2048 + (row0 & 2047);
        *(unsigned int*)&Vt[vb]     = pack2(acc[mt][nt][0], acc[mt][nt][1]);
        *(unsigned int*)&Vt[vb + 2] = pack2(acc[mt][nt][2], acc[mt][nt][3]);
      } else {
#pragma unroll
        for (int i = 0; i < 4; ++i) {
          const int lq = (row0 + i) & 2047;
          float v = acc[mt][nt][i];
          if (which == 0) Q [(bh * 2048 + lq) * 64 + hd] = f2b(v * 0.125f);
          else            Kc[(bh * 2048 + lq) * 64 + hd] = f2b(v);
        }
      }
    }
}

// ---------------- causal flash attention (KVBLK=64, LDS-shared K/V) ----------------
// == UNCHANGED from round-20 PASSING kernel ==
__global__ __launch_bounds__(256, 4) void k_attn(
    const unsigned short* __restrict__ Q, const unsigned short* __restrict__ Kc,
    const unsigned short* __restrict__ Vt, unsigned short* __restrict__ attn) {
  __shared__ __align__(16) unsigned short kbuf[2][64 * 64];   // 8KB per buf
  __shared__ __align__(16) unsigned short vbuf[2][64 * 64];   // 8KB per buf

  const int bh  = blockIdx.x & 31;
  const int grp = 31 - (blockIdx.x >> 5);      // 0..31, longest first
  const int wv = threadIdx.x >> 6, lane = threadIdx.x & 63;
  const int tid = threadIdx.x;
  const int strip = (grp << 2) + wv;           // 0..127
  const int qw = strip << 4;
  const int b = bh >> 4, h = bh & 15;
  const unsigned short* Qb = Q  + (size_t)bh * 2048 * 64;
  const unsigned short* Kb = Kc + (size_t)bh * 2048 * 64;
  const unsigned short* Vb = Vt + (size_t)bh * 64 * 2048;
  const int fr = lane & 15, g = lane >> 4;
  const int fk = g << 3, r4 = g << 2;
  const f32x4 fz = {0.f, 0.f, 0.f, 0.f};

  // staging map: 512 granules per buffer, 2 per thread
  const int sgr0 = tid >> 3,        sgc0 = tid & 7;          // granule (row, col)
  const int sgr1 = (tid + 256) >> 3, sgc1 = tid & 7;         // second granule

  sh8 qf[2];
#pragma unroll
  for (int ks = 0; ks < 2; ++ks)
    qf[ks] = *(const sh8*)&Qb[(size_t)(qw + fr) * 64 + ks * 32 + fk];

  f32x4 o[4];
#pragma unroll
  for (int i = 0; i < 4; ++i) o[i] = fz;
  float m_i = -1e30f, lp = 0.f;

  const int njm = grp + 1;                     // uniform tile count (incl. diagonal)

  // stage tile 0 into buf 0
  gload_lds16(&Kb[(size_t)sgr0 * 64 + ((sgc0 ^ (sgr0 & 7)) << 3)], &kbuf[0][tid * 8]);
  gload_lds16(&Kb[(size_t)sgr1 * 64 + ((sgc1 ^ (sgr1 & 7)) << 3)], &kbuf[0][(tid + 256) * 8]);
  gload_lds16(&Vb[(size_t)sgr0 * 2048 + ((sgc0 ^ (sgr0 & 7)) << 3)], &vbuf[0][tid * 8]);
  gload_lds16(&Vb[(size_t)sgr1 * 2048 + ((sgc1 ^ (sgr1 & 7)) << 3)], &vbuf[0][(tid + 256) * 8]);

  for (int j = 0; j < njm; ++j) {
    __syncthreads();   // stage(j) complete (vmcnt drain); compute(j-1) done
    if (j + 1 < njm) {
      const int kvn = (j + 1) << 6;
      const int nb = (j + 1) & 1;
      gload_lds16(&Kb[(size_t)(kvn + sgr0) * 64 + ((sgc0 ^ (sgr0 & 7)) << 3)], &kbuf[nb][tid * 8]);
      gload_lds16(&Kb[(size_t)(kvn + sgr1) * 64 + ((sgc1 ^ (sgr1 & 7)) << 3)], &kbuf[nb][(tid + 256) * 8]);
      gload_lds16(&Vb[(size_t)sgr0 * 2048 + kvn + ((sgc0 ^ (sgr0 & 7)) << 3)], &vbuf[nb][tid * 8]);
      gload_lds16(&Vb[(size_t)sgr1 * 2048 + kvn + ((sgc1 ^ (sgr1 & 7)) << 3)], &vbuf[nb][(tid + 256) * 8]);
    }
    const int kvb = j << 6;
    const unsigned short* kb = kbuf[j & 1];
    const unsigned short* vb = vbuf[j & 1];
    // QK^T swapped, 4 independent sub-tiles: s[t] rows kv = kvb+16t+4g+i, col q = fr
    f32x4 s[4];
#pragma unroll
    for (int t = 0; t < 4; ++t) s[t] = fz;
#pragma unroll
    for (int ks = 0; ks < 2; ++ks)
#pragma unroll
      for (int t = 0; t < 4; ++t) {
        sh8 kf = *(const sh8*)&kb[(t * 16 + fr) * 64 + ((((ks << 2) + g) ^ (fr & 7)) << 3)];
        s[t] = __builtin_amdgcn_mfma_f32_16x16x32_bf16(kf, qf[ks], s[t], 0, 0, 0);
      }

    if (j == njm - 1) {  // diagonal tile: causal mask (kv > q)
#pragma unroll
      for (int t = 0; t < 4; ++t)
#pragma unroll
        for (int i = 0; i < 4; ++i)
          if (kvb + t * 16 + r4 + i > qw + fr) s[t][i] = -1e30f;
    }
    // defer-max (T13): common path has NO cross-lane ops
    float pm = s[0][0];
#pragma unroll
    for (int t = 0; t < 4; ++t)
#pragma unroll
      for (int i = 0; i < 4; ++i) pm = fmaxf(pm, s[t][i]);
    if (!__all(pm - m_i <= 8.0f)) {   // rare: full row-max reduce + rescale
      float rm = fmaxf(pm, __shfl_xor(pm, 16, 64));
      rm = fmaxf(rm, __shfl_xor(rm, 32, 64));
      const float mn = fmaxf(m_i, rm);
      const float sc = __expf(m_i - mn);
      m_i = mn;
      lp *= sc;
#pragma unroll
      for (int hb = 0; hb < 4; ++hb)
#pragma unroll
        for (int i = 0; i < 4; ++i) o[hb][i] *= sc;
    }
    // exp in place; lp per-lane partial
#pragma unroll
    for (int t = 0; t < 4; ++t) {
#pragma unroll
      for (int i = 0; i < 4; ++i) s[t][i] = __expf(s[t][i] - m_i);
      lp += (s[t][0] + s[t][1]) + (s[t][2] + s[t][3]);
    }
    // PV per sub-tile: P already in x16 B-frag layout (col q=fr, k=4g+j)
#pragma unroll
    for (int t = 0; t < 4; ++t) {
      union { unsigned int w[2]; sh4 v; } pb;
      pb.w[0] = pack2(s[t][0], s[t][1]);
      pb.w[1] = pack2(s[t][2], s[t][3]);
#pragma unroll
      for (int hb = 0; hb < 4; ++hb) {
        sh4 vf = *(const sh4*)&vb[(hb * 16 + fr) * 64 +
                                  ((((t << 1) + (g >> 1)) ^ (fr & 7)) << 3) + ((g & 1) << 2)];
        o[hb] = mfma16x16x16(vf, pb.v, o[hb]);
      }
    }
  }

  // epilogue: reduce per-lane lp across the 4 g-groups once (r7/r17-validated)
  float l = lp;
  l += __shfl_xor(l, 16, 64);
  l += __shfl_xor(l, 32, 64);
  const float inv = 1.0f / l;
  const size_t base = ((size_t)(b * 2048 + qw + fr)) * 1024 + h * 64;
#pragma unroll
  for (int hb = 0; hb < 4; ++hb)
#pragma unroll
    for (int i2 = 0; i2 < 2; ++i2) {
      unsigned int pw = pack2(o[hb][2 * i2] * inv, o[hb][2 * i2 + 1] * inv);
      *(unsigned int*)&attn[base + hb * 16 + r4 + 2 * i2] = pw;
    }
}

// ---------------- output projection + bias (BM=64, BN=64 -> 1024 blocks) ----------
__global__ __launch_bounds__(256, 5) void k_out_gemm(
    const unsigned short* __restrict__ attn, const unsigned short* __restrict__ wo,
    const float* __restrict__ bias, float* __restrict__ out) {
  __shared__ __align__(16) unsigned short ldsA[2 * 64 * 64];    // 16KB (dbuf)
  __shared__ __align__(16) unsigned short ldsB[2 * 64 * 64];    // 16KB (dbuf)
  f32x4 acc[2][2];
  const f32x4 fz = {0.f, 0.f, 0.f, 0.f};
#pragma unroll
  for (int i = 0; i < 2; ++i)
#pragma unroll
    for (int j = 0; j < 2; ++j) acc[i][j] = fz;

  const int m0 = blockIdx.x * 64, n0 = blockIdx.y * 64;
  gemm_bt_core<2, 2>(attn, wo, 1024, m0, n0, ldsA, ldsB, acc);

  const int tid = threadIdx.x, wv = tid >> 6, lane = tid & 63;
  const int wm = (wv >> 1) << 5, wn = (wv & 1) << 5;
  const int r4 = (lane >> 4) << 2, fr = lane & 15;
#pragma unroll
  for (int mt = 0; mt < 2; ++mt)
#pragma unroll
    for (int nt = 0; nt < 2; ++nt)
#pragma unroll
      for (int i = 0; i < 4; ++i) {
        int row = m0 + wm + mt * 16 + r4 + i;
        int col = n0 + wn + nt * 16 + fr;
        out[(size_t)row * 1024 + col] = acc[mt][nt][i] + bias[col];
      }
}

// ---------------- launch ----------------
extern "C" void kernel_launch(void* const* d_in, const int* in_sizes, int n_in,
                              void* d_out, int out_size, void* d_ws, size_t ws_size,
                              hipStream_t stream) {
  const float* x     = (const float*)d_in[0];
  const float* qkv_w = (const float*)d_in[1];
  const float* out_w = (const float*)d_in[2];
  const float* out_b = (const float*)d_in[3];
  float* out = (float*)d_out;

  unsigned short* ws   = (unsigned short*)d_ws;
  unsigned short* xb   = ws;                        // 4096*1024
  unsigned short* wq   = xb  + 4096 * 1024;         // 3072*1024
  unsigned short* wo   = wq  + 3072 * 1024;         // 1024*1024
  unsigned short* Qs   = wo  + 1024 * 1024;         // 32*2048*64
  unsigned short* Ks   = Qs  + 32 * 2048 * 64;      // 32*2048*64
  unsigned short* Vts  = Ks  + 32 * 2048 * 64;      // 32*64*2048
  unsigned short* attn = Vts + 32 * 64 * 2048;      // 4096*1024

  k_cvt<<<4096, 256, 0, stream>>>(x,     xb, 4096 * 1024);
  k_cvt<<<3072, 256, 0, stream>>>(qkv_w, wq, 3072 * 1024);
  k_cvt<<<1024, 256, 0, stream>>>(out_w, wo, 1024 * 1024);
  k_qkv_gemm<<<dim3(64, 24), 256, 0, stream>>>(xb, wq, Qs, Ks, Vts);
  k_attn<<<1024, 256, 0, stream>>>(Qs, Ks, Vts, attn);
  k_out_gemm<<<dim3(64, 16), 256, 0, stream>>>(attn, wo, out_b, out);
}